// Round 14
// baseline (1952.472 us; speedup 1.0000x reference)
//
#include <hip/hip_runtime.h>
#include <hip/hip_bf16.h>
#include <math.h>

#define NHEADS 12
#define NTOK   50
#define NWIN   2048
#define IMGS   32
#define CDIM   384
#define QKVD   1152
#define DHID   768
#define MLPH   3072
#define KTAIL  3456   // 384 + 3072
#define SCALE_F 0.17677669529663687f

typedef short short8 __attribute__((ext_vector_type(8)));
typedef short short4v __attribute__((ext_vector_type(4)));
typedef short short2v __attribute__((ext_vector_type(2)));
typedef float f32x4  __attribute__((ext_vector_type(4)));
typedef __hip_bfloat16 bf16;

// tanh-form gelu (|err| ~1e-3) — LN paths (cold)
__device__ __forceinline__ float gelu_f(float x){
  float z = 0.7978845608028654f*(x + 0.044715f*x*x*x);
  float e = __expf(2.0f*z);
  return 0.5f*x*(1.0f + (1.0f - 2.0f/(e+1.0f)));
}
// sigmoid-form gelu — hot fc1 epilogue (~5 VALU ops)
__device__ __forceinline__ float gelu_fast(float x){
  float e = __expf(-1.702f*x);
  return x / (1.0f + e);
}
__device__ __forceinline__ short bfs(float x){
  bf16 h = __float2bfloat16(x); return *(short*)&h;
}

// ---------------- weights fp32 -> bf16 (4 tensors) ----------------
__global__ void cvt4_kernel(const float* s0, bf16* d0, int n0,
                            const float* s1, bf16* d1, int n1,
                            const float* s2, bf16* d2, int n2,
                            const float* s3, bf16* d3, int n3){
  int stride = gridDim.x*blockDim.x, g = blockIdx.x*blockDim.x + threadIdx.x;
  for (int i=g; i<n0; i+=stride) d0[i] = __float2bfloat16(s0[i]);
  for (int i=g; i<n1; i+=stride) d1[i] = __float2bfloat16(s1[i]);
  for (int i=g; i<n2; i+=stride) d2[i] = __float2bfloat16(s2[i]);
  for (int i=g; i<n3; i+=stride) d3[i] = __float2bfloat16(s3[i]);
}

// ---------------- transpose + cvt: src[R][Cc] fp32 -> dst[Cc][R] bf16 ------------
__global__ __launch_bounds__(256) void transpose_cvt_kernel(const float* __restrict__ src,
    bf16* __restrict__ dst, int R, int Cc){
  __shared__ float tile[32][33];
  int bx = blockIdx.x, by = blockIdx.y;
  int c = threadIdx.x & 31, r0 = threadIdx.x >> 5;
  #pragma unroll
  for (int rr = r0; rr < 32; rr += 8)
    tile[rr][c] = src[(size_t)(by*32+rr)*Cc + bx*32 + c];
  __syncthreads();
  #pragma unroll
  for (int rr = r0; rr < 32; rr += 8)
    dst[(size_t)(bx*32+rr)*R + by*32 + c] = __float2bfloat16(tile[c][rr]);
}

// ---------------- bias_c = b_lin + w_lin * (b_exp + b_fc2) ----------------
__global__ void bias_combine_kernel(const float* __restrict__ wlin,
    const float* __restrict__ b_lin, const float* __restrict__ b_exp,
    const float* __restrict__ b_fc2, float* __restrict__ biasc){
  int i = blockIdx.x*blockDim.x + threadIdx.x;
  if (i >= CDIM) return;
  float s = b_lin[i];
  for (int d=0; d<DHID; d++) s += wlin[(size_t)i*DHID+d]*(b_exp[d]+b_fc2[d]);
  biasc[i] = s;
}

// ---------------- split-K reduce: out = p0 + p1 + biasc ----------------
__global__ __launch_bounds__(256) void sk_reduce_kernel(
    const float4* __restrict__ p0, const float4* __restrict__ p1,
    const float4* __restrict__ bc, float4* __restrict__ out, int n)
{
  for (int i = blockIdx.x*blockDim.x + threadIdx.x; i < n; i += gridDim.x*blockDim.x){
    float4 x = p0[i], y = p1[i], z = bc[i % 96];
    float4 r;
    r.x = x.x + y.x + z.x;  r.y = x.y + y.y + z.y;
    r.z = x.z + y.z + z.z;  r.w = x.w + y.w + z.w;
    out[i] = r;
  }
}

// ---------------- LayerNorm, fp32 in -> bf16 out ----------------
template<bool GELU>
__global__ __launch_bounds__(256) void ln_kernel(const float* __restrict__ x, long ldx,
    const float* __restrict__ g, const float* __restrict__ b,
    bf16* __restrict__ y, int rows)
{
  int row = blockIdx.x*4 + (threadIdx.x>>6);
  if (row >= rows) return;
  int l = threadIdx.x & 63;
  const float2* xr = (const float2*)(x + (size_t)row*ldx);
  float2 v[3]; float s = 0.f;
  #pragma unroll
  for (int j=0;j<3;j++){ v[j] = xr[l + 64*j]; s += v[j].x + v[j].y; }
  #pragma unroll
  for (int off=32; off; off>>=1) s += __shfl_xor(s, off, 64);
  float mean = s * (1.0f/384.0f);
  float vs = 0.f;
  #pragma unroll
  for (int j=0;j<3;j++){ float dx=v[j].x-mean, dy=v[j].y-mean; vs += dx*dx+dy*dy; }
  #pragma unroll
  for (int off=32; off; off>>=1) vs += __shfl_xor(vs, off, 64);
  float rstd = rsqrtf(vs*(1.0f/384.0f) + 1e-5f);
  short2v* yr = (short2v*)(y + (size_t)row*384);
  const float2* gv = (const float2*)g; const float2* bv = (const float2*)b;
  #pragma unroll
  for (int j=0;j<3;j++){
    float2 gg = gv[l+64*j], bb = bv[l+64*j];
    float o0 = (v[j].x-mean)*rstd*gg.x + bb.x;
    float o1 = (v[j].y-mean)*rstd*gg.y + bb.y;
    if (GELU){ o0 = gelu_f(o0); o1 = gelu_f(o1); }
    short2v pk; pk[0]=bfs(o0); pk[1]=bfs(o1);
    yr[l+64*j] = pk;
  }
}

// ------- dual LayerNorm: one read, two outputs (expand-gelu @lde, mlp @384) -------
__global__ __launch_bounds__(256) void ln_dual_kernel(const float* __restrict__ x,
    const float* __restrict__ ge, const float* __restrict__ be,
    const float* __restrict__ g2, const float* __restrict__ b2,
    bf16* __restrict__ yeo, long lde, bf16* __restrict__ y2o, int rows)
{
  int row = blockIdx.x*4 + (threadIdx.x>>6);
  if (row >= rows) return;
  int l = threadIdx.x & 63;
  const float2* xr = (const float2*)(x + (size_t)row*384);
  float2 v[3]; float s = 0.f;
  #pragma unroll
  for (int j=0;j<3;j++){ v[j] = xr[l + 64*j]; s += v[j].x + v[j].y; }
  #pragma unroll
  for (int off=32; off; off>>=1) s += __shfl_xor(s, off, 64);
  float mean = s * (1.0f/384.0f);
  float vs = 0.f;
  #pragma unroll
  for (int j=0;j<3;j++){ float dx=v[j].x-mean, dy=v[j].y-mean; vs += dx*dx+dy*dy; }
  #pragma unroll
  for (int off=32; off; off>>=1) vs += __shfl_xor(vs, off, 64);
  float rstd = rsqrtf(vs*(1.0f/384.0f) + 1e-5f);
  short2v* ye = (short2v*)(yeo + (size_t)row*lde);
  short2v* y2 = (short2v*)(y2o + (size_t)row*384);
  const float2* gev = (const float2*)ge; const float2* bev = (const float2*)be;
  const float2* g2v = (const float2*)g2; const float2* b2v = (const float2*)b2;
  #pragma unroll
  for (int j=0;j<3;j++){
    float n0 = (v[j].x-mean)*rstd, n1 = (v[j].y-mean)*rstd;
    float2 gg = gev[l+64*j], bb = bev[l+64*j];
    short2v pe; pe[0]=bfs(gelu_f(n0*gg.x+bb.x)); pe[1]=bfs(gelu_f(n1*gg.y+bb.y));
    ye[l+64*j] = pe;
    gg = g2v[l+64*j]; bb = b2v[l+64*j];
    short2v p2; p2[0]=bfs(n0*gg.x+bb.x); p2[1]=bfs(n1*gg.y+bb.y);
    y2[l+64*j] = p2;
  }
}

// ---------------- GEMM: C[M,N] = A[M,K](bf16, row-stride lda) * B[N,K]^T (ldb) ----
// 128x128 tile, 4 waves, depth-2 prefetch (3 LDS buffers, counted vmcnt(4)),
// XCD-bijective swizzle. [round-8 proven structure]  GELU: 0=none 1=sigmoid-fast
template<bool OUT_BF16, bool BIAS, int RES, int GELU>
__device__ __forceinline__ void gemm_dev(
    const bf16* __restrict__ A, const bf16* __restrict__ B, void* Cv,
    const float* __restrict__ bias, const void* res,
    int M, int N, int K, int lda, int ldb, int ldc, int ldres)
{
  __shared__ short As[3][128*32];
  __shared__ short Bs[3][128*32];
  const int t  = threadIdx.x;
  const int l  = t & 63;
  const int w  = t >> 6;
  const int wr = w >> 1, wc = w & 1;
  const int lr = l & 15, kg = l >> 4;

  const int nwg = gridDim.x * gridDim.y;
  const int lin = blockIdx.y * gridDim.x + blockIdx.x;
  const int q8 = nwg >> 3, r8 = nwg & 7;
  const int xcd = lin & 7, slot = lin >> 3;
  const int swz = (xcd < r8) ? (xcd*(q8+1) + slot) : (r8*(q8+1) + (xcd-r8)*q8 + slot);
  const int by = swz / gridDim.x, bx = swz - by*gridDim.x;

  const int bm = by * 128, bn = bx * 128;
  const short* Ag = (const short*)A;
  const short* Bg = (const short*)B;

  const int eo0 = w*1024 + l*8;
  const int rowS0 = eo0 >> 5, colS0 = eo0 & 31;
  const int eo1 = eo0 + 512;
  const int rowS1 = eo1 >> 5, colS1 = eo1 & 31;

  #define STAGE(k0, b) do { \
    __builtin_amdgcn_global_load_lds( \
      (const __attribute__((address_space(1))) void*)&Ag[(size_t)(bm+rowS0)*lda + (k0) + colS0], \
      (__attribute__((address_space(3))) void*)((char*)&As[b][0] + w*2048), 16, 0, 0); \
    __builtin_amdgcn_global_load_lds( \
      (const __attribute__((address_space(1))) void*)&Bg[(size_t)(bn+rowS0)*ldb + (k0) + colS0], \
      (__attribute__((address_space(3))) void*)((char*)&Bs[b][0] + w*2048), 16, 0, 0); \
    __builtin_amdgcn_global_load_lds( \
      (const __attribute__((address_space(1))) void*)&Ag[(size_t)(bm+rowS1)*lda + (k0) + colS1], \
      (__attribute__((address_space(3))) void*)((char*)&As[b][0] + w*2048 + 1024), 16, 0, 0); \
    __builtin_amdgcn_global_load_lds( \
      (const __attribute__((address_space(1))) void*)&Bg[(size_t)(bn+rowS1)*ldb + (k0) + colS1], \
      (__attribute__((address_space(3))) void*)((char*)&Bs[b][0] + w*2048 + 1024), 16, 0, 0); \
  } while(0)

  f32x4 acc[4][4] = {};

  STAGE(0, 0);
  STAGE(32, 1);
  asm volatile("s_waitcnt vmcnt(4)" ::: "memory");
  __builtin_amdgcn_s_barrier();

  int cur = 0, nb = 2;
  for (int k0 = 0; k0 < K; k0 += 32) {
    const bool more = (k0 + 64 < K);
    if (more) STAGE(k0 + 64, nb);

    short8 af[4], bfm[4];
    #pragma unroll
    for (int m=0;m<4;m++) af[m]  = *(const short8*)(&As[cur][(wr*64 + m*16 + lr)*32 + kg*8]);
    #pragma unroll
    for (int n=0;n<4;n++) bfm[n] = *(const short8*)(&Bs[cur][(wc*64 + n*16 + lr)*32 + kg*8]);
    __builtin_amdgcn_s_setprio(1);
    #pragma unroll
    for (int m=0;m<4;m++)
      #pragma unroll
      for (int n=0;n<4;n++)
        acc[m][n] = __builtin_amdgcn_mfma_f32_16x16x32_bf16(af[m], bfm[n], acc[m][n], 0,0,0);
    __builtin_amdgcn_s_setprio(0);

    if (more) { asm volatile("s_waitcnt vmcnt(4)" ::: "memory"); }
    else      { asm volatile("s_waitcnt vmcnt(0)" ::: "memory"); }
    __builtin_amdgcn_s_barrier();
    cur = (cur==2) ? 0 : cur+1;
    nb  = (nb==2)  ? 0 : nb+1;
  }
  #undef STAGE

  #pragma unroll
  for (int m=0;m<4;m++){
    int row0 = bm + wr*64 + m*16 + kg*4;
    #pragma unroll
    for (int n=0;n<4;n++){
      int col = bn + wc*64 + n*16 + lr;
      float bv = BIAS ? bias[col] : 0.0f;
      #pragma unroll
      for (int r=0;r<4;r++){
        float val = acc[m][n][r] + bv;
        if (RES == 1) val += ((const float*)res)[(size_t)(row0+r)*ldres + col];
        if (GELU == 1) val = gelu_fast(val);
        if (OUT_BF16) ((bf16*)Cv)[(size_t)(row0+r)*ldc + col] = __float2bfloat16(val);
        else          ((float*)Cv)[(size_t)(row0+r)*ldc + col] = val;
      }
    }
  }
}

#define GEMM_K(NAME, OB, BI, RE, GE) \
__global__ __launch_bounds__(256) void NAME( \
    const bf16* __restrict__ A, const bf16* __restrict__ B, void* Cv, \
    const float* __restrict__ bias, const void* res, \
    int M, int N, int K, int lda, int ldc, int ldres){ \
  gemm_dev<OB,BI,RE,GE>(A,B,Cv,bias,res,M,N,K,lda,K,ldc,ldres); }

GEMM_K(gemm_qkv_k,  true,  false, 0, 0)   // qkv: bf16 out
GEMM_K(gemm_proj_k, false, true,  1, 0)   // proj: +bias, +fp32 res, fp32 out
GEMM_K(gemm_fc1_k,  true,  true,  0, 1)   // fc1: +bias, fast-gelu, bf16 out (ldc=KTAIL)
GEMM_K(gemm_wcmb_k, true,  false, 0, 0)   // weight-combo precompute, bf16 out

// split-K tail: gridDim.z = 2; segment z covers K cols [z*1728, z*1728+1728) of
// A (lda=KTAIL) and W_comb (ldb=KTAIL!); fp32 partial (no bias) -> part + z*M*384.
__global__ __launch_bounds__(256) void gemm_tail_sk(
    const bf16* __restrict__ A, const bf16* __restrict__ B, float* part,
    int M)
{
  const int seg = blockIdx.z;
  gemm_dev<false,false,0,0>(
      A + seg*(KTAIL/2), B + seg*(KTAIL/2), part + (size_t)seg*M*CDIM,
      nullptr, nullptr, M, CDIM, KTAIL/2, KTAIL, KTAIL, CDIM, 0);
}

// ---------------- cls attention (small; unchanged) ----------------
__global__ __launch_bounds__(256) void attn_cls_kernel(const bf16* __restrict__ qkv,
                                                       bf16* __restrict__ y)
{
  int img = blockIdx.x, h = blockIdx.y;
  __shared__ float q[64][33], k[64][33], v[64][33];
  __shared__ float s[64][65];
  int t = threadIdx.x;
  for (int idx=t; idx<64*32; idx+=256){
    int i = idx>>5, d = idx&31;
    const bf16* base = qkv + ((size_t)(img*64+i))*QKVD + h*32 + d;
    q[i][d] = __bfloat162float(base[0]);
    k[i][d] = __bfloat162float(base[384]);
    v[i][d] = __bfloat162float(base[768]);
  }
  __syncthreads();
  for (int idx=t; idx<64*64; idx+=256){
    int i = idx>>6, j = idx&63;
    float a = 0.f;
    #pragma unroll
    for (int d=0; d<32; d++) a += q[i][d]*k[j][d];
    s[i][j] = a * SCALE_F;
  }
  __syncthreads();
  if (t < 64){
    float m = -1e30f;
    for (int j=0;j<64;j++) m = fmaxf(m, s[t][j]);
    float sum = 0.f;
    for (int j=0;j<64;j++){ float e = __expf(s[t][j]-m); s[t][j]=e; sum+=e; }
    float inv = 1.0f/sum;
    for (int j=0;j<64;j++) s[t][j] *= inv;
  }
  __syncthreads();
  for (int idx=t; idx<64*32; idx+=256){
    int i = idx>>5, d = idx&31;
    float a = 0.f;
    for (int j=0;j<64;j++) a += s[i][j]*v[j][d];
    y[((size_t)(img*64+i))*CDIM + h*32 + d] = __float2bfloat16(a);
  }
}

// ======== MFMA window attention (proven round-8) ========
__global__ __launch_bounds__(64) void attn_win_mfma(const bf16* __restrict__ qkv,
    const float* __restrict__ mask, const float* __restrict__ rel_pos,
    bf16* __restrict__ y)
{
  const int lw = blockIdx.x, h = blockIdx.y;
  const int l = threadIdx.x;
  const int lr = l & 15, kg = l >> 4;
  __shared__ short Plds[64*72];
  __shared__ short VTl[32*72];
  __shared__ float rp[169];

  const size_t tok0 = (size_t)lw * NTOK;
  const short* qbase = (const short*)qkv;

  for (int i=l; i<169; i+=64) rp[i] = rel_pos[i*NHEADS + h];

  short8 qf[4], kf[4];
  #pragma unroll
  for (int n=0;n<4;n++){
    int qt = 16*n + lr;
    if (qt < 50) qf[n] = *(const short8*)&qbase[(tok0+qt)*QKVD + h*32 + kg*8];
    else         qf[n] = short8(0);
  }
  #pragma unroll
  for (int m=0;m<4;m++){
    int kt = 16*m + lr;
    if (kt < 50) kf[m] = *(const short8*)&qbase[(tok0+kt)*QKVD + 384 + h*32 + kg*8];
    else         kf[m] = short8(0);
  }

  {
    short vv[32];
    if (l < 50){
      const short8* vp = (const short8*)&qbase[(tok0+l)*QKVD + 768 + h*32];
      #pragma unroll
      for (int jj=0;jj<4;jj++){ short8 xv = vp[jj];
        #pragma unroll
        for (int e=0;e<8;e++) vv[jj*8+e] = xv[e]; }
    } else {
      #pragma unroll
      for (int d=0; d<32; d++) vv[d]=0;
    }
    #pragma unroll
    for (int d=0; d<32; d++) VTl[d*72 + l] = vv[d];
  }

  f32x4 sacc[4][4] = {};
  #pragma unroll
  for (int m=0;m<4;m++)
    #pragma unroll
    for (int n=0;n<4;n++)
      sacc[m][n] = __builtin_amdgcn_mfma_f32_16x16x32_bf16(kf[m], qf[n], sacc[m][n], 0,0,0);

  const float* mrow = mask + (size_t)lw*2500;
  float sv[4][4][4];
  #pragma unroll
  for (int m=0;m<4;m++){
    #pragma unroll
    for (int r=0;r<4;r++){
      int kt = 16*m + 4*kg + r;
      #pragma unroll
      for (int n=0;n<4;n++){
        int qt = 16*n + lr;
        float a;
        if (kt < 50 && qt < 50){
          a = sacc[m][n][r] * SCALE_F;
          if (kt>=1 && qt>=1){
            int qi=qt-1, kj=kt-1;
            int ridx = ((qi/7)-(kj/7)+6)*13 + (qi%7)-(kj%7)+6;
            a += rp[ridx];
          }
          a += mrow[qt*50+kt];
        } else a = -1e30f;
        sv[m][r][n] = a;
      }
    }
  }

  #pragma unroll
  for (int n=0;n<4;n++){
    float mx = -1e30f;
    #pragma unroll
    for (int m=0;m<4;m++)
      #pragma unroll
      for (int r=0;r<4;r++) mx = fmaxf(mx, sv[m][r][n]);
    mx = fmaxf(mx, __shfl_xor(mx, 16));
    mx = fmaxf(mx, __shfl_xor(mx, 32));
    float sum = 0.f;
    float pv[4][4];
    #pragma unroll
    for (int m=0;m<4;m++)
      #pragma unroll
      for (int r=0;r<4;r++){ float p = __expf(sv[m][r][n]-mx); pv[m][r]=p; sum+=p; }
    sum += __shfl_xor(sum, 16);
    sum += __shfl_xor(sum, 32);
    float inv = 1.0f/sum;
    int qrow = (16*n + lr)*72;
    #pragma unroll
    for (int m=0;m<4;m++){
      short4v pk;
      #pragma unroll
      for (int r=0;r<4;r++) pk[r] = bfs(pv[m][r]*inv);
      *(short4v*)&Plds[qrow + 16*m + 4*kg] = pk;
    }
  }
  __syncthreads();

  f32x4 oacc[2][4] = {};
  #pragma unroll
  for (int ks=0; ks<2; ks++){
    short8 pf[4];
    #pragma unroll
    for (int n=0;n<4;n++)
      pf[n] = *(const short8*)&Plds[(16*n+lr)*72 + 32*ks + kg*8];
    #pragma unroll
    for (int md=0; md<2; md++){
      short8 vf = *(const short8*)&VTl[(16*md+lr)*72 + 32*ks + kg*8];
      #pragma unroll
      for (int n=0;n<4;n++)
        oacc[md][n] = __builtin_amdgcn_mfma_f32_16x16x32_bf16(vf, pf[n], oacc[md][n], 0,0,0);
    }
  }

  short* yb = (short*)y;
  #pragma unroll
  for (int n=0;n<4;n++){
    int qt = 16*n + lr;
    if (qt >= 50) continue;
    #pragma unroll
    for (int md=0; md<2; md++){
      short4v pk;
      #pragma unroll
      for (int r=0;r<4;r++) pk[r] = bfs(oacc[md][n][r]);
      *(short4v*)&yb[(tok0+qt)*CDIM + h*32 + 16*md + 4*kg] = pk;
    }
  }
}

// ---------------------------------------------------------------------------
extern "C" void kernel_launch(void* const* d_in, const int* in_sizes, int n_in,
                              void* d_out, int out_size, void* d_ws, size_t ws_size,
                              hipStream_t stream)
{
  const float* x_in   = (const float*)d_in[0];
  const float* maskp  = (const float*)d_in[1];
  const float* g0 = (const float*)d_in[2];  const float* b0 = (const float*)d_in[3];
  const float* g1 = (const float*)d_in[4];  const float* b1 = (const float*)d_in[5];
  const float* g2 = (const float*)d_in[6];  const float* b2 = (const float*)d_in[7];
  const float* ge = (const float*)d_in[8];  const float* be = (const float*)d_in[9];
  const float* w_qkv = (const float*)d_in[10];
  const float* w_proj= (const float*)d_in[11];
  const float* b_proj= (const float*)d_in[12];
  const float* rel_pos=(const float*)d_in[13];
  const float* w_fc1 = (const float*)d_in[14];
  const float* b_fc1 = (const float*)d_in[15];
  const float* w_fc2 = (const float*)d_in[16];
  const float* b_fc2 = (const float*)d_in[17];
  const float* w_exp = (const float*)d_in[18];
  const float* b_exp = (const float*)d_in[19];
  const float* w_lin = (const float*)d_in[20];
  const float* b_lin = (const float*)d_in[21];
  float* dout = (float*)d_out;

  const size_t NT = (size_t)NWIN * NTOK;

  size_t off = 0;
  auto alloc = [&](size_t bytes)->void* {
    void* p = (char*)d_ws + off;
    off += (bytes + 255) & ~(size_t)255;
    return p;
  };

  bf16* wqkv_b = (bf16*)alloc((size_t)QKVD*CDIM*2);
  bf16* wproj_b= (bf16*)alloc((size_t)CDIM*CDIM*2);
  bf16* wfc1_b = (bf16*)alloc((size_t)MLPH*CDIM*2);
  bf16* wlin_b = (bf16*)alloc((size_t)CDIM*DHID*2);
  bf16* wexpT_b= (bf16*)alloc((size_t)CDIM*DHID*2);   // w_exp^T  [384,768]
  bf16* wfc2T_b= (bf16*)alloc((size_t)MLPH*DHID*2);   // w_fc2^T  [3072,768]
  bf16* W_comb = (bf16*)alloc((size_t)CDIM*KTAIL*2);  // [384][3456] = [W_el | W_h]
  float* biasc = (float*)alloc((size_t)CDIM*4);
  float* xb    = (float*)alloc(NT*CDIM*4);
  bf16* clsln  = (bf16*)alloc((size_t)NWIN*CDIM*2);
  bf16* qkvcls = (bf16*)alloc((size_t)NWIN*QKVD*2);
  bf16* ycls   = (bf16*)alloc((size_t)NWIN*CDIM*2);

  // per-window: xln 38400 + qkvc 115200 + ybfc 38400 + h1ext 345600 = 537600
  int CH_W = 2048;
  const size_t per_window = 537600ull;
  while (CH_W > 128 && off + (size_t)CH_W*per_window + 16384 > ws_size) CH_W >>= 1;
  const int CH_T = CH_W * NTOK;

  bf16*  xln   = (bf16*) alloc((size_t)CH_T*CDIM*2);
  bf16*  qkvc  = (bf16*) alloc((size_t)CH_T*QKVD*2);
  bf16*  ybfc  = (bf16*) alloc((size_t)CH_T*CDIM*2);
  bf16*  h1ext = (bf16*) alloc((size_t)CH_T*KTAIL*2);  // [M][3456]: [geluLNe | gelu(fc1)]
  // split-K partials overlay EXACTLY on xln+qkvc (both dead when tail runs):
  // bytes needed = 2 * CH_T*384*4 = CH_T*3072 = bytes(xln)+bytes(qkvc)  (exact,
  // and xln's size CH_T*768 B is 256-aligned so qkvc is contiguous after xln)
  float* skpart = (float*)xln;

  // ---- precompute ----
  cvt4_kernel<<<512, 256, 0, stream>>>(
      w_qkv, wqkv_b, QKVD*CDIM,  w_proj, wproj_b, CDIM*CDIM,
      w_fc1, wfc1_b, MLPH*CDIM,  w_lin,  wlin_b,  CDIM*DHID);
  transpose_cvt_kernel<<<dim3(CDIM/32, DHID/32), 256, 0, stream>>>(w_exp, wexpT_b, DHID, CDIM);
  transpose_cvt_kernel<<<dim3(MLPH/32, DHID/32), 256, 0, stream>>>(w_fc2, wfc2T_b, DHID, MLPH);
  bias_combine_kernel<<<6, 64, 0, stream>>>(w_lin, b_lin, b_exp, b_fc2, biasc);
  gemm_wcmb_k<<<dim3(CDIM/128, CDIM/128), 256, 0, stream>>>(
      wlin_b, wexpT_b, W_comb, nullptr, nullptr, CDIM, CDIM, DHID, DHID, KTAIL, 0);
  gemm_wcmb_k<<<dim3(MLPH/128, CDIM/128), 256, 0, stream>>>(
      wlin_b, wfc2T_b, W_comb + 384, nullptr, nullptr, CDIM, MLPH, DHID, DHID, KTAIL, 0);

  hipMemcpyAsync(xb, x_in, NT*CDIM*4, hipMemcpyDeviceToDevice, stream);

  // ---- cls path ----
  ln_kernel<false><<<NWIN/4, 256, 0, stream>>>(x_in, (long)NTOK*CDIM, g0, b0, clsln, NWIN);
  gemm_qkv_k<<<dim3(QKVD/128, NWIN/128), 256, 0, stream>>>(
      clsln, wqkv_b, qkvcls, nullptr, nullptr, NWIN, QKVD, CDIM, CDIM, QKVD, 0);
  attn_cls_kernel<<<dim3(IMGS, NHEADS), 256, 0, stream>>>(qkvcls, ycls);
  gemm_proj_k<<<dim3(CDIM/128, NWIN/128), 256, 0, stream>>>(
      ycls, wproj_b, xb, b_proj, x_in, NWIN, CDIM, CDIM, CDIM, NTOK*CDIM, NTOK*CDIM);

  // ---- main chunk loop ----
  const int nch = NWIN / CH_W;
  for (int c = 0; c < nch; c++){
    int w0 = c * CH_W;
    size_t t0 = (size_t)w0 * NTOK;
    float* xbc = xb + t0*CDIM;
    float* doutc = dout + t0*CDIM;
    int MT = CH_T, MB = CH_T/128;

    ln_kernel<false><<<MT/4, 256, 0, stream>>>(xbc, CDIM, g1, b1, xln, MT);
    gemm_qkv_k<<<dim3(QKVD/128, MB), 256, 0, stream>>>(
        xln, wqkv_b, qkvc, nullptr, nullptr, MT, QKVD, CDIM, CDIM, QKVD, 0);
    attn_win_mfma<<<dim3(CH_W, NHEADS), 64, 0, stream>>>(
        qkvc, maskp + (size_t)w0*2500, rel_pos, ybfc);
    gemm_proj_k<<<dim3(CDIM/128, MB), 256, 0, stream>>>(
        ybfc, wproj_b, xbc, b_proj, xbc, MT, CDIM, CDIM, CDIM, CDIM, CDIM);

    // dual LN: expand-gelu into h1ext[:,0:384] (ld 3456), mlp-LN into ybfc
    ln_dual_kernel<<<MT/4, 256, 0, stream>>>(xbc, ge, be, g2, b2, h1ext, KTAIL, ybfc, MT);

    // h1ext[:,384:3456] = gelu_fast(LN2(x) @ w_fc1^T + b_fc1)
    gemm_fc1_k<<<dim3(MLPH/128, MB), 256, 0, stream>>>(
        ybfc, wfc1_b, h1ext + 384, b_fc1, nullptr, MT, MLPH, CDIM, CDIM, KTAIL, 0);

    // split-K tail: partials (xln/qkvc dead here), then fused reduce+bias -> dout
    gemm_tail_sk<<<dim3(CDIM/128, MB, 2), 256, 0, stream>>>(
        h1ext, W_comb, skpart, MT);
    sk_reduce_kernel<<<2048, 256, 0, stream>>>(
        (const float4*)skpart, (const float4*)(skpart + (size_t)MT*CDIM),
        (const float4*)biasc, (float4*)doutc, MT*CDIM/4);
  }
}

// Round 15
// 1687.185 us; speedup vs baseline: 1.1572x; 1.1572x over previous
//
#include <hip/hip_runtime.h>
#include <hip/hip_bf16.h>
#include <math.h>

#define NHEADS 12
#define NTOK   50
#define NWIN   2048
#define IMGS   32
#define CDIM   384
#define QKVD   1152
#define DHID   768
#define MLPH   3072
#define KTAIL  3456   // 384 + 3072
#define SCALE_F 0.17677669529663687f

typedef short short8 __attribute__((ext_vector_type(8)));
typedef short short4v __attribute__((ext_vector_type(4)));
typedef short short2v __attribute__((ext_vector_type(2)));
typedef float f32x4  __attribute__((ext_vector_type(4)));
typedef __hip_bfloat16 bf16;

// tanh-form gelu (|err| ~1e-3) — LN paths (cold)
__device__ __forceinline__ float gelu_f(float x){
  float z = 0.7978845608028654f*(x + 0.044715f*x*x*x);
  float e = __expf(2.0f*z);
  return 0.5f*x*(1.0f + (1.0f - 2.0f/(e+1.0f)));
}
// sigmoid-form gelu — hot fc1 epilogue (~5 VALU ops)
__device__ __forceinline__ float gelu_fast(float x){
  float e = __expf(-1.702f*x);
  return x / (1.0f + e);
}
__device__ __forceinline__ short bfs(float x){
  bf16 h = __float2bfloat16(x); return *(short*)&h;
}

// ---------------- weights fp32 -> bf16 (4 tensors) ----------------
__global__ void cvt4_kernel(const float* s0, bf16* d0, int n0,
                            const float* s1, bf16* d1, int n1,
                            const float* s2, bf16* d2, int n2,
                            const float* s3, bf16* d3, int n3){
  int stride = gridDim.x*blockDim.x, g = blockIdx.x*blockDim.x + threadIdx.x;
  for (int i=g; i<n0; i+=stride) d0[i] = __float2bfloat16(s0[i]);
  for (int i=g; i<n1; i+=stride) d1[i] = __float2bfloat16(s1[i]);
  for (int i=g; i<n2; i+=stride) d2[i] = __float2bfloat16(s2[i]);
  for (int i=g; i<n3; i+=stride) d3[i] = __float2bfloat16(s3[i]);
}

// ---------------- transpose + cvt: src[R][Cc] fp32 -> dst[Cc][R] bf16 ------------
__global__ __launch_bounds__(256) void transpose_cvt_kernel(const float* __restrict__ src,
    bf16* __restrict__ dst, int R, int Cc){
  __shared__ float tile[32][33];
  int bx = blockIdx.x, by = blockIdx.y;
  int c = threadIdx.x & 31, r0 = threadIdx.x >> 5;
  #pragma unroll
  for (int rr = r0; rr < 32; rr += 8)
    tile[rr][c] = src[(size_t)(by*32+rr)*Cc + bx*32 + c];
  __syncthreads();
  #pragma unroll
  for (int rr = r0; rr < 32; rr += 8)
    dst[(size_t)(bx*32+rr)*R + by*32 + c] = __float2bfloat16(tile[c][rr]);
}

// ---------------- bias_c = b_lin + w_lin * (b_exp + b_fc2) ----------------
__global__ void bias_combine_kernel(const float* __restrict__ wlin,
    const float* __restrict__ b_lin, const float* __restrict__ b_exp,
    const float* __restrict__ b_fc2, float* __restrict__ biasc){
  int i = blockIdx.x*blockDim.x + threadIdx.x;
  if (i >= CDIM) return;
  float s = b_lin[i];
  for (int d=0; d<DHID; d++) s += wlin[(size_t)i*DHID+d]*(b_exp[d]+b_fc2[d]);
  biasc[i] = s;
}

// ---------------- LayerNorm, fp32 in -> bf16 out ----------------
template<bool GELU>
__global__ __launch_bounds__(256) void ln_kernel(const float* __restrict__ x, long ldx,
    const float* __restrict__ g, const float* __restrict__ b,
    bf16* __restrict__ y, int rows)
{
  int row = blockIdx.x*4 + (threadIdx.x>>6);
  if (row >= rows) return;
  int l = threadIdx.x & 63;
  const float2* xr = (const float2*)(x + (size_t)row*ldx);
  float2 v[3]; float s = 0.f;
  #pragma unroll
  for (int j=0;j<3;j++){ v[j] = xr[l + 64*j]; s += v[j].x + v[j].y; }
  #pragma unroll
  for (int off=32; off; off>>=1) s += __shfl_xor(s, off, 64);
  float mean = s * (1.0f/384.0f);
  float vs = 0.f;
  #pragma unroll
  for (int j=0;j<3;j++){ float dx=v[j].x-mean, dy=v[j].y-mean; vs += dx*dx+dy*dy; }
  #pragma unroll
  for (int off=32; off; off>>=1) vs += __shfl_xor(vs, off, 64);
  float rstd = rsqrtf(vs*(1.0f/384.0f) + 1e-5f);
  short2v* yr = (short2v*)(y + (size_t)row*384);
  const float2* gv = (const float2*)g; const float2* bv = (const float2*)b;
  #pragma unroll
  for (int j=0;j<3;j++){
    float2 gg = gv[l+64*j], bb = bv[l+64*j];
    float o0 = (v[j].x-mean)*rstd*gg.x + bb.x;
    float o1 = (v[j].y-mean)*rstd*gg.y + bb.y;
    if (GELU){ o0 = gelu_f(o0); o1 = gelu_f(o1); }
    short2v pk; pk[0]=bfs(o0); pk[1]=bfs(o1);
    yr[l+64*j] = pk;
  }
}

// ---- LayerNorm with row-conditional source: cls rows (row%50==0) from xa, else xbse
__global__ __launch_bounds__(256) void ln_sel_kernel(const float* __restrict__ xa,
    const float* __restrict__ xbse,
    const float* __restrict__ g, const float* __restrict__ b,
    bf16* __restrict__ y, int rows)
{
  int row = blockIdx.x*4 + (threadIdx.x>>6);
  if (row >= rows) return;
  int l = threadIdx.x & 63;
  const float* src = (row % 50 == 0) ? xa : xbse;
  const float2* xr = (const float2*)(src + (size_t)row*384);
  float2 v[3]; float s = 0.f;
  #pragma unroll
  for (int j=0;j<3;j++){ v[j] = xr[l + 64*j]; s += v[j].x + v[j].y; }
  #pragma unroll
  for (int off=32; off; off>>=1) s += __shfl_xor(s, off, 64);
  float mean = s * (1.0f/384.0f);
  float vs = 0.f;
  #pragma unroll
  for (int j=0;j<3;j++){ float dx=v[j].x-mean, dy=v[j].y-mean; vs += dx*dx+dy*dy; }
  #pragma unroll
  for (int off=32; off; off>>=1) vs += __shfl_xor(vs, off, 64);
  float rstd = rsqrtf(vs*(1.0f/384.0f) + 1e-5f);
  short2v* yr = (short2v*)(y + (size_t)row*384);
  const float2* gv = (const float2*)g; const float2* bv = (const float2*)b;
  #pragma unroll
  for (int j=0;j<3;j++){
    float2 gg = gv[l+64*j], bb = bv[l+64*j];
    short2v pk;
    pk[0]=bfs((v[j].x-mean)*rstd*gg.x + bb.x);
    pk[1]=bfs((v[j].y-mean)*rstd*gg.y + bb.y);
    yr[l+64*j] = pk;
  }
}

// ------- dual LayerNorm: one read, two outputs (expand-gelu @lde, mlp @384) -------
__global__ __launch_bounds__(256) void ln_dual_kernel(const float* __restrict__ x,
    const float* __restrict__ ge, const float* __restrict__ be,
    const float* __restrict__ g2, const float* __restrict__ b2,
    bf16* __restrict__ yeo, long lde, bf16* __restrict__ y2o, int rows)
{
  int row = blockIdx.x*4 + (threadIdx.x>>6);
  if (row >= rows) return;
  int l = threadIdx.x & 63;
  const float2* xr = (const float2*)(x + (size_t)row*384);
  float2 v[3]; float s = 0.f;
  #pragma unroll
  for (int j=0;j<3;j++){ v[j] = xr[l + 64*j]; s += v[j].x + v[j].y; }
  #pragma unroll
  for (int off=32; off; off>>=1) s += __shfl_xor(s, off, 64);
  float mean = s * (1.0f/384.0f);
  float vs = 0.f;
  #pragma unroll
  for (int j=0;j<3;j++){ float dx=v[j].x-mean, dy=v[j].y-mean; vs += dx*dx+dy*dy; }
  #pragma unroll
  for (int off=32; off; off>>=1) vs += __shfl_xor(vs, off, 64);
  float rstd = rsqrtf(vs*(1.0f/384.0f) + 1e-5f);
  short2v* ye = (short2v*)(yeo + (size_t)row*lde);
  short2v* y2 = (short2v*)(y2o + (size_t)row*384);
  const float2* gev = (const float2*)ge; const float2* bev = (const float2*)be;
  const float2* g2v = (const float2*)g2; const float2* b2v = (const float2*)b2;
  #pragma unroll
  for (int j=0;j<3;j++){
    float n0 = (v[j].x-mean)*rstd, n1 = (v[j].y-mean)*rstd;
    float2 gg = gev[l+64*j], bb = bev[l+64*j];
    short2v pe; pe[0]=bfs(gelu_f(n0*gg.x+bb.x)); pe[1]=bfs(gelu_f(n1*gg.y+bb.y));
    ye[l+64*j] = pe;
    gg = g2v[l+64*j]; bb = b2v[l+64*j];
    short2v p2; p2[0]=bfs(n0*gg.x+bb.x); p2[1]=bfs(n1*gg.y+bb.y);
    y2[l+64*j] = p2;
  }
}

// ---------------- GEMM: C[M,N] = A[M,K](bf16, lda) * B[N,K]^T (ldb), fp32 acc -----
// 128x128 tile, 4 waves, depth-2 prefetch (3 LDS buffers, counted vmcnt(4)),
// XCD-bijective swizzle. [proven]  GELU: 0=none 1=sigmoid-fast
// RES: 0=none 1=fp32  3=row-conditional fp32 (cls row%50==0 -> res, else res2)
template<bool OUT_BF16, bool BIAS, int RES, int GELU>
__device__ __forceinline__ void gemm_dev(
    const bf16* __restrict__ A, const bf16* __restrict__ B, void* Cv,
    const float* __restrict__ bias, const void* res, const void* res2,
    int M, int N, int K, int lda, int ldb, int ldc, int ldres)
{
  __shared__ short As[3][128*32];
  __shared__ short Bs[3][128*32];
  const int t  = threadIdx.x;
  const int l  = t & 63;
  const int w  = t >> 6;
  const int wr = w >> 1, wc = w & 1;
  const int lr = l & 15, kg = l >> 4;

  const int nwg = gridDim.x * gridDim.y;
  const int lin = blockIdx.y * gridDim.x + blockIdx.x;
  const int q8 = nwg >> 3, r8 = nwg & 7;
  const int xcd = lin & 7, slot = lin >> 3;
  const int swz = (xcd < r8) ? (xcd*(q8+1) + slot) : (r8*(q8+1) + (xcd-r8)*q8 + slot);
  const int by = swz / gridDim.x, bx = swz - by*gridDim.x;

  const int bm = by * 128, bn = bx * 128;
  const short* Ag = (const short*)A;
  const short* Bg = (const short*)B;

  const int eo0 = w*1024 + l*8;
  const int rowS0 = eo0 >> 5, colS0 = eo0 & 31;
  const int eo1 = eo0 + 512;
  const int rowS1 = eo1 >> 5, colS1 = eo1 & 31;

  #define STAGE(k0, b) do { \
    __builtin_amdgcn_global_load_lds( \
      (const __attribute__((address_space(1))) void*)&Ag[(size_t)(bm+rowS0)*lda + (k0) + colS0], \
      (__attribute__((address_space(3))) void*)((char*)&As[b][0] + w*2048), 16, 0, 0); \
    __builtin_amdgcn_global_load_lds( \
      (const __attribute__((address_space(1))) void*)&Bg[(size_t)(bn+rowS0)*ldb + (k0) + colS0], \
      (__attribute__((address_space(3))) void*)((char*)&Bs[b][0] + w*2048), 16, 0, 0); \
    __builtin_amdgcn_global_load_lds( \
      (const __attribute__((address_space(1))) void*)&Ag[(size_t)(bm+rowS1)*lda + (k0) + colS1], \
      (__attribute__((address_space(3))) void*)((char*)&As[b][0] + w*2048 + 1024), 16, 0, 0); \
    __builtin_amdgcn_global_load_lds( \
      (const __attribute__((address_space(1))) void*)&Bg[(size_t)(bn+rowS1)*ldb + (k0) + colS1], \
      (__attribute__((address_space(3))) void*)((char*)&Bs[b][0] + w*2048 + 1024), 16, 0, 0); \
  } while(0)

  f32x4 acc[4][4] = {};

  STAGE(0, 0);
  STAGE(32, 1);
  asm volatile("s_waitcnt vmcnt(4)" ::: "memory");
  __builtin_amdgcn_s_barrier();

  int cur = 0, nb = 2;
  for (int k0 = 0; k0 < K; k0 += 32) {
    const bool more = (k0 + 64 < K);
    if (more) STAGE(k0 + 64, nb);

    short8 af[4], bfm[4];
    #pragma unroll
    for (int m=0;m<4;m++) af[m]  = *(const short8*)(&As[cur][(wr*64 + m*16 + lr)*32 + kg*8]);
    #pragma unroll
    for (int n=0;n<4;n++) bfm[n] = *(const short8*)(&Bs[cur][(wc*64 + n*16 + lr)*32 + kg*8]);
    __builtin_amdgcn_s_setprio(1);
    #pragma unroll
    for (int m=0;m<4;m++)
      #pragma unroll
      for (int n=0;n<4;n++)
        acc[m][n] = __builtin_amdgcn_mfma_f32_16x16x32_bf16(af[m], bfm[n], acc[m][n], 0,0,0);
    __builtin_amdgcn_s_setprio(0);

    if (more) { asm volatile("s_waitcnt vmcnt(4)" ::: "memory"); }
    else      { asm volatile("s_waitcnt vmcnt(0)" ::: "memory"); }
    __builtin_amdgcn_s_barrier();
    cur = (cur==2) ? 0 : cur+1;
    nb  = (nb==2)  ? 0 : nb+1;
  }
  #undef STAGE

  #pragma unroll
  for (int m=0;m<4;m++){
    int row0 = bm + wr*64 + m*16 + kg*4;
    #pragma unroll
    for (int n=0;n<4;n++){
      int col = bn + wc*64 + n*16 + lr;
      float bv = BIAS ? bias[col] : 0.0f;
      #pragma unroll
      for (int r=0;r<4;r++){
        float val = acc[m][n][r] + bv;
        if (RES == 1) val += ((const float*)res)[(size_t)(row0+r)*ldres + col];
        if (RES == 3){
          int grow = row0 + r;
          const float* rs = ((grow % 50) == 0) ? (const float*)res : (const float*)res2;
          val += rs[(size_t)grow*ldres + col];
        }
        if (GELU == 1) val = gelu_fast(val);
        if (OUT_BF16) ((bf16*)Cv)[(size_t)(row0+r)*ldc + col] = __float2bfloat16(val);
        else          ((float*)Cv)[(size_t)(row0+r)*ldc + col] = val;
      }
    }
  }
}

#define GEMM_K(NAME, OB, BI, RE, GE) \
__global__ __launch_bounds__(256) void NAME( \
    const bf16* __restrict__ A, const bf16* __restrict__ B, void* Cv, \
    const float* __restrict__ bias, const void* res, const void* res2, \
    int M, int N, int K, int lda, int ldc, int ldres){ \
  gemm_dev<OB,BI,RE,GE>(A,B,Cv,bias,res,res2,M,N,K,lda,K,ldc,ldres); }

GEMM_K(gemm_qkv_k,   true,  false, 0, 0)   // qkv: bf16 out
GEMM_K(gemm_projc_k, false, true,  1, 0)   // cls proj: +bias, +fp32 res, fp32 out
GEMM_K(gemm_projw_k, false, true,  3, 0)   // window proj: row-conditional residual
GEMM_K(gemm_fc1_k,   true,  true,  0, 1)   // fc1: +bias, fast-gelu, bf16 out (ldc=KTAIL)
GEMM_K(gemm_tail_k,  false, true,  0, 0)   // fused tail: +bias_c, fp32 out (dout)
GEMM_K(gemm_wcmb_k,  true,  false, 0, 0)   // weight-combo precompute, bf16 out

// ---------------- cls attention (small; unchanged) ----------------
__global__ __launch_bounds__(256) void attn_cls_kernel(const bf16* __restrict__ qkv,
                                                       bf16* __restrict__ y)
{
  int img = blockIdx.x, h = blockIdx.y;
  __shared__ float q[64][33], k[64][33], v[64][33];
  __shared__ float s[64][65];
  int t = threadIdx.x;
  for (int idx=t; idx<64*32; idx+=256){
    int i = idx>>5, d = idx&31;
    const bf16* base = qkv + ((size_t)(img*64+i))*QKVD + h*32 + d;
    q[i][d] = __bfloat162float(base[0]);
    k[i][d] = __bfloat162float(base[384]);
    v[i][d] = __bfloat162float(base[768]);
  }
  __syncthreads();
  for (int idx=t; idx<64*64; idx+=256){
    int i = idx>>6, j = idx&63;
    float a = 0.f;
    #pragma unroll
    for (int d=0; d<32; d++) a += q[i][d]*k[j][d];
    s[i][j] = a * SCALE_F;
  }
  __syncthreads();
  if (t < 64){
    float m = -1e30f;
    for (int j=0;j<64;j++) m = fmaxf(m, s[t][j]);
    float sum = 0.f;
    for (int j=0;j<64;j++){ float e = __expf(s[t][j]-m); s[t][j]=e; sum+=e; }
    float inv = 1.0f/sum;
    for (int j=0;j<64;j++) s[t][j] *= inv;
  }
  __syncthreads();
  for (int idx=t; idx<64*32; idx+=256){
    int i = idx>>5, d = idx&31;
    float a = 0.f;
    for (int j=0;j<64;j++) a += s[i][j]*v[j][d];
    y[((size_t)(img*64+i))*CDIM + h*32 + d] = __float2bfloat16(a);
  }
}

// ======== MFMA window attention (proven round-8) ========
__global__ __launch_bounds__(64) void attn_win_mfma(const bf16* __restrict__ qkv,
    const float* __restrict__ mask, const float* __restrict__ rel_pos,
    bf16* __restrict__ y)
{
  const int lw = blockIdx.x, h = blockIdx.y;
  const int l = threadIdx.x;
  const int lr = l & 15, kg = l >> 4;
  __shared__ short Plds[64*72];
  __shared__ short VTl[32*72];
  __shared__ float rp[169];

  const size_t tok0 = (size_t)lw * NTOK;
  const short* qbase = (const short*)qkv;

  for (int i=l; i<169; i+=64) rp[i] = rel_pos[i*NHEADS + h];

  short8 qf[4], kf[4];
  #pragma unroll
  for (int n=0;n<4;n++){
    int qt = 16*n + lr;
    if (qt < 50) qf[n] = *(const short8*)&qbase[(tok0+qt)*QKVD + h*32 + kg*8];
    else         qf[n] = short8(0);
  }
  #pragma unroll
  for (int m=0;m<4;m++){
    int kt = 16*m + lr;
    if (kt < 50) kf[m] = *(const short8*)&qbase[(tok0+kt)*QKVD + 384 + h*32 + kg*8];
    else         kf[m] = short8(0);
  }

  {
    short vv[32];
    if (l < 50){
      const short8* vp = (const short8*)&qbase[(tok0+l)*QKVD + 768 + h*32];
      #pragma unroll
      for (int jj=0;jj<4;jj++){ short8 xv = vp[jj];
        #pragma unroll
        for (int e=0;e<8;e++) vv[jj*8+e] = xv[e]; }
    } else {
      #pragma unroll
      for (int d=0; d<32; d++) vv[d]=0;
    }
    #pragma unroll
    for (int d=0; d<32; d++) VTl[d*72 + l] = vv[d];
  }

  f32x4 sacc[4][4] = {};
  #pragma unroll
  for (int m=0;m<4;m++)
    #pragma unroll
    for (int n=0;n<4;n++)
      sacc[m][n] = __builtin_amdgcn_mfma_f32_16x16x32_bf16(kf[m], qf[n], sacc[m][n], 0,0,0);

  const float* mrow = mask + (size_t)lw*2500;
  float sv[4][4][4];
  #pragma unroll
  for (int m=0;m<4;m++){
    #pragma unroll
    for (int r=0;r<4;r++){
      int kt = 16*m + 4*kg + r;
      #pragma unroll
      for (int n=0;n<4;n++){
        int qt = 16*n + lr;
        float a;
        if (kt < 50 && qt < 50){
          a = sacc[m][n][r] * SCALE_F;
          if (kt>=1 && qt>=1){
            int qi=qt-1, kj=kt-1;
            int ridx = ((qi/7)-(kj/7)+6)*13 + (qi%7)-(kj%7)+6;
            a += rp[ridx];
          }
          a += mrow[qt*50+kt];
        } else a = -1e30f;
        sv[m][r][n] = a;
      }
    }
  }

  #pragma unroll
  for (int n=0;n<4;n++){
    float mx = -1e30f;
    #pragma unroll
    for (int m=0;m<4;m++)
      #pragma unroll
      for (int r=0;r<4;r++) mx = fmaxf(mx, sv[m][r][n]);
    mx = fmaxf(mx, __shfl_xor(mx, 16));
    mx = fmaxf(mx, __shfl_xor(mx, 32));
    float sum = 0.f;
    float pv[4][4];
    #pragma unroll
    for (int m=0;m<4;m++)
      #pragma unroll
      for (int r=0;r<4;r++){ float p = __expf(sv[m][r][n]-mx); pv[m][r]=p; sum+=p; }
    sum += __shfl_xor(sum, 16);
    sum += __shfl_xor(sum, 32);
    float inv = 1.0f/sum;
    int qrow = (16*n + lr)*72;
    #pragma unroll
    for (int m=0;m<4;m++){
      short4v pk;
      #pragma unroll
      for (int r=0;r<4;r++) pk[r] = bfs(pv[m][r]*inv);
      *(short4v*)&Plds[qrow + 16*m + 4*kg] = pk;
    }
  }
  __syncthreads();

  f32x4 oacc[2][4] = {};
  #pragma unroll
  for (int ks=0; ks<2; ks++){
    short8 pf[4];
    #pragma unroll
    for (int n=0;n<4;n++)
      pf[n] = *(const short8*)&Plds[(16*n+lr)*72 + 32*ks + kg*8];
    #pragma unroll
    for (int md=0; md<2; md++){
      short8 vf = *(const short8*)&VTl[(16*md+lr)*72 + 32*ks + kg*8];
      #pragma unroll
      for (int n=0;n<4;n++)
        oacc[md][n] = __builtin_amdgcn_mfma_f32_16x16x32_bf16(vf, pf[n], oacc[md][n], 0,0,0);
    }
  }

  short* yb = (short*)y;
  #pragma unroll
  for (int n=0;n<4;n++){
    int qt = 16*n + lr;
    if (qt >= 50) continue;
    #pragma unroll
    for (int md=0; md<2; md++){
      short4v pk;
      #pragma unroll
      for (int r=0;r<4;r++) pk[r] = bfs(oacc[md][n][r]);
      *(short4v*)&yb[(tok0+qt)*CDIM + h*32 + 16*md + 4*kg] = pk;
    }
  }
}

// ---------------------------------------------------------------------------
extern "C" void kernel_launch(void* const* d_in, const int* in_sizes, int n_in,
                              void* d_out, int out_size, void* d_ws, size_t ws_size,
                              hipStream_t stream)
{
  const float* x_in   = (const float*)d_in[0];
  const float* maskp  = (const float*)d_in[1];
  const float* g0 = (const float*)d_in[2];  const float* b0 = (const float*)d_in[3];
  const float* g1 = (const float*)d_in[4];  const float* b1 = (const float*)d_in[5];
  const float* g2 = (const float*)d_in[6];  const float* b2 = (const float*)d_in[7];
  const float* ge = (const float*)d_in[8];  const float* be = (const float*)d_in[9];
  const float* w_qkv = (const float*)d_in[10];
  const float* w_proj= (const float*)d_in[11];
  const float* b_proj= (const float*)d_in[12];
  const float* rel_pos=(const float*)d_in[13];
  const float* w_fc1 = (const float*)d_in[14];
  const float* b_fc1 = (const float*)d_in[15];
  const float* w_fc2 = (const float*)d_in[16];
  const float* b_fc2 = (const float*)d_in[17];
  const float* w_exp = (const float*)d_in[18];
  const float* b_exp = (const float*)d_in[19];
  const float* w_lin = (const float*)d_in[20];
  const float* b_lin = (const float*)d_in[21];
  float* dout = (float*)d_out;

  const size_t NT = (size_t)NWIN * NTOK;

  size_t off = 0;
  auto alloc = [&](size_t bytes)->void* {
    void* p = (char*)d_ws + off;
    off += (bytes + 255) & ~(size_t)255;
    return p;
  };

  bf16* wqkv_b = (bf16*)alloc((size_t)QKVD*CDIM*2);
  bf16* wproj_b= (bf16*)alloc((size_t)CDIM*CDIM*2);
  bf16* wfc1_b = (bf16*)alloc((size_t)MLPH*CDIM*2);
  bf16* wlin_b = (bf16*)alloc((size_t)CDIM*DHID*2);
  bf16* wexpT_b= (bf16*)alloc((size_t)CDIM*DHID*2);   // w_exp^T  [384,768]
  bf16* wfc2T_b= (bf16*)alloc((size_t)MLPH*DHID*2);   // w_fc2^T  [3072,768]
  bf16* W_comb = (bf16*)alloc((size_t)CDIM*KTAIL*2);  // [384][3456] = [W_el | W_h]
  float* biasc = (float*)alloc((size_t)CDIM*4);
  float* xb    = (float*)alloc(NT*CDIM*4);
  bf16* clsln  = (bf16*)alloc((size_t)NWIN*CDIM*2);
  bf16* qkvcls = (bf16*)alloc((size_t)NWIN*QKVD*2);
  bf16* ycls   = (bf16*)alloc((size_t)NWIN*CDIM*2);

  // per-window: xln 38400 + ybfc 38400 + h1ext 345600 = 422400 (qkvc aliases h1ext)
  int CH_W = 2048;
  const size_t per_window = 422400ull;
  while (CH_W > 128 && off + (size_t)CH_W*per_window + 16384 > ws_size) CH_W >>= 1;
  const int CH_T = CH_W * NTOK;

  bf16*  xln   = (bf16*) alloc((size_t)CH_T*CDIM*2);
  bf16*  ybfc  = (bf16*) alloc((size_t)CH_T*CDIM*2);
  bf16*  h1ext = (bf16*) alloc((size_t)CH_T*KTAIL*2);  // [M][3456]: [geluLNe | gelu(fc1)]
  // qkv activations alias the FRONT of h1ext (CH_T*1152*2 B <= CH_T*3456*2 B):
  // qkvc is dead before ln_dual/fc1 write h1ext (stream-ordered), so no overlap-in-time.
  bf16*  qkvc  = h1ext;

  // ---- precompute ----
  cvt4_kernel<<<512, 256, 0, stream>>>(
      w_qkv, wqkv_b, QKVD*CDIM,  w_proj, wproj_b, CDIM*CDIM,
      w_fc1, wfc1_b, MLPH*CDIM,  w_lin,  wlin_b,  CDIM*DHID);
  transpose_cvt_kernel<<<dim3(CDIM/32, DHID/32), 256, 0, stream>>>(w_exp, wexpT_b, DHID, CDIM);
  transpose_cvt_kernel<<<dim3(MLPH/32, DHID/32), 256, 0, stream>>>(w_fc2, wfc2T_b, DHID, MLPH);
  bias_combine_kernel<<<6, 64, 0, stream>>>(w_lin, b_lin, b_exp, b_fc2, biasc);
  gemm_wcmb_k<<<dim3(CDIM/128, CDIM/128), 256, 0, stream>>>(
      wlin_b, wexpT_b, W_comb, nullptr, nullptr, nullptr, CDIM, CDIM, DHID, DHID, KTAIL, 0);
  gemm_wcmb_k<<<dim3(MLPH/128, CDIM/128), 256, 0, stream>>>(
      wlin_b, wfc2T_b, W_comb + 384, nullptr, nullptr, nullptr, CDIM, MLPH, DHID, DHID, KTAIL, 0);

  // ---- cls path (writes only cls rows of xb; other rows never read) ----
  ln_kernel<false><<<NWIN/4, 256, 0, stream>>>(x_in, (long)NTOK*CDIM, g0, b0, clsln, NWIN);
  gemm_qkv_k<<<dim3(QKVD/128, NWIN/128), 256, 0, stream>>>(
      clsln, wqkv_b, qkvcls, nullptr, nullptr, nullptr, NWIN, QKVD, CDIM, CDIM, QKVD, 0);
  attn_cls_kernel<<<dim3(IMGS, NHEADS), 256, 0, stream>>>(qkvcls, ycls);
  gemm_projc_k<<<dim3(CDIM/128, NWIN/128), 256, 0, stream>>>(
      ycls, wproj_b, xb, b_proj, x_in, nullptr, NWIN, CDIM, CDIM, CDIM, NTOK*CDIM, NTOK*CDIM);

  // ---- main chunk loop ----
  const int nch = NWIN / CH_W;
  for (int c = 0; c < nch; c++){
    int w0 = c * CH_W;
    size_t t0 = (size_t)w0 * NTOK;
    float* xbc = xb + t0*CDIM;
    const float* xinc = x_in + t0*CDIM;
    float* doutc = dout + t0*CDIM;
    int MT = CH_T, MB = CH_T/128;

    // LN1: cls rows from xb (updated by cls path; xb cls-row stride within chunk is
    // 50*384 and chunk base = window start, so local row%50==0 <=> cls), else x_in
    ln_sel_kernel<<<MT/4, 256, 0, stream>>>(xbc, xinc, g1, b1, xln, MT);
    gemm_qkv_k<<<dim3(QKVD/128, MB), 256, 0, stream>>>(
        xln, wqkv_b, qkvc, nullptr, nullptr, nullptr, MT, QKVD, CDIM, CDIM, QKVD, 0);
    attn_win_mfma<<<dim3(CH_W, NHEADS), 64, 0, stream>>>(
        qkvc, maskp + (size_t)w0*2500, rel_pos, ybfc);
    // window proj: residual row-conditional (cls rows from xb, else x_in); writes xbc
    gemm_projw_k<<<dim3(CDIM/128, MB), 256, 0, stream>>>(
        ybfc, wproj_b, xbc, b_proj, xbc, xinc, MT, CDIM, CDIM, CDIM, CDIM, CDIM);

    // dual LN: expand-gelu into h1ext[:,0:384] (ld 3456), mlp-LN into ybfc
    ln_dual_kernel<<<MT/4, 256, 0, stream>>>(xbc, ge, be, g2, b2, h1ext, KTAIL, ybfc, MT);

    // h1ext[:,384:3456] = gelu_fast(LN2(x) @ w_fc1^T + b_fc1)
    gemm_fc1_k<<<dim3(MLPH/128, MB), 256, 0, stream>>>(
        ybfc, wfc1_b, h1ext + 384, b_fc1, nullptr, nullptr, MT, MLPH, CDIM, CDIM, KTAIL, 0);

    // dout = h1ext @ W_comb^T + bias_c   (K=3456, fused expand+mlp+lin)
    gemm_tail_k<<<dim3(CDIM/128, MB), 256, 0, stream>>>(
        h1ext, W_comb, doutc, biasc, nullptr, nullptr, MT, CDIM, KTAIL, KTAIL, CDIM, 0);
  }
}

// Round 16
// 1654.253 us; speedup vs baseline: 1.1803x; 1.0199x over previous
//
#include <hip/hip_runtime.h>
#include <hip/hip_bf16.h>
#include <math.h>

#define NHEADS 12
#define NTOK   50
#define NWIN   2048
#define IMGS   32
#define CDIM   384
#define QKVD   1152
#define DHID   768
#define MLPH   3072
#define KTAIL  3456   // 384 + 3072
#define SCALE_F 0.17677669529663687f

typedef short short8 __attribute__((ext_vector_type(8)));
typedef short short4v __attribute__((ext_vector_type(4)));
typedef short short2v __attribute__((ext_vector_type(2)));
typedef float f32x4  __attribute__((ext_vector_type(4)));
typedef __hip_bfloat16 bf16;

__device__ __forceinline__ float rcp_fast(float x){ return __builtin_amdgcn_rcpf(x); }

// tanh-form gelu (|err| ~1e-3) — LN paths (cold); rcp instead of full divide
__device__ __forceinline__ float gelu_f(float x){
  float z = 0.7978845608028654f*(x + 0.044715f*x*x*x);
  float e = __expf(2.0f*z);
  return 0.5f*x*(1.0f + (1.0f - 2.0f*rcp_fast(e+1.0f)));
}
// sigmoid-form gelu — hot fc1 epilogue; v_rcp instead of precise division
__device__ __forceinline__ float gelu_fast(float x){
  float e = __expf(-1.702f*x);
  return x * rcp_fast(1.0f + e);
}
__device__ __forceinline__ short bfs(float x){
  bf16 h = __float2bfloat16(x); return *(short*)&h;
}

// ---------------- weights fp32 -> bf16 (4 tensors) ----------------
__global__ void cvt4_kernel(const float* s0, bf16* d0, int n0,
                            const float* s1, bf16* d1, int n1,
                            const float* s2, bf16* d2, int n2,
                            const float* s3, bf16* d3, int n3){
  int stride = gridDim.x*blockDim.x, g = blockIdx.x*blockDim.x + threadIdx.x;
  for (int i=g; i<n0; i+=stride) d0[i] = __float2bfloat16(s0[i]);
  for (int i=g; i<n1; i+=stride) d1[i] = __float2bfloat16(s1[i]);
  for (int i=g; i<n2; i+=stride) d2[i] = __float2bfloat16(s2[i]);
  for (int i=g; i<n3; i+=stride) d3[i] = __float2bfloat16(s3[i]);
}

// ---------------- transpose + cvt: src[R][Cc] fp32 -> dst[Cc][R] bf16 ------------
__global__ __launch_bounds__(256) void transpose_cvt_kernel(const float* __restrict__ src,
    bf16* __restrict__ dst, int R, int Cc){
  __shared__ float tile[32][33];
  int bx = blockIdx.x, by = blockIdx.y;
  int c = threadIdx.x & 31, r0 = threadIdx.x >> 5;
  #pragma unroll
  for (int rr = r0; rr < 32; rr += 8)
    tile[rr][c] = src[(size_t)(by*32+rr)*Cc + bx*32 + c];
  __syncthreads();
  #pragma unroll
  for (int rr = r0; rr < 32; rr += 8)
    dst[(size_t)(bx*32+rr)*R + by*32 + c] = __float2bfloat16(tile[c][rr]);
}

// ---------------- bias_c = b_lin + w_lin * (b_exp + b_fc2) ----------------
__global__ void bias_combine_kernel(const float* __restrict__ wlin,
    const float* __restrict__ b_lin, const float* __restrict__ b_exp,
    const float* __restrict__ b_fc2, float* __restrict__ biasc){
  int i = blockIdx.x*blockDim.x + threadIdx.x;
  if (i >= CDIM) return;
  float s = b_lin[i];
  for (int d=0; d<DHID; d++) s += wlin[(size_t)i*DHID+d]*(b_exp[d]+b_fc2[d]);
  biasc[i] = s;
}

// ---------------- LayerNorm, fp32 in -> bf16 out ----------------
template<bool GELU>
__global__ __launch_bounds__(256) void ln_kernel(const float* __restrict__ x, long ldx,
    const float* __restrict__ g, const float* __restrict__ b,
    bf16* __restrict__ y, int rows)
{
  int row = blockIdx.x*4 + (threadIdx.x>>6);
  if (row >= rows) return;
  int l = threadIdx.x & 63;
  const float2* xr = (const float2*)(x + (size_t)row*ldx);
  float2 v[3]; float s = 0.f;
  #pragma unroll
  for (int j=0;j<3;j++){ v[j] = xr[l + 64*j]; s += v[j].x + v[j].y; }
  #pragma unroll
  for (int off=32; off; off>>=1) s += __shfl_xor(s, off, 64);
  float mean = s * (1.0f/384.0f);
  float vs = 0.f;
  #pragma unroll
  for (int j=0;j<3;j++){ float dx=v[j].x-mean, dy=v[j].y-mean; vs += dx*dx+dy*dy; }
  #pragma unroll
  for (int off=32; off; off>>=1) vs += __shfl_xor(vs, off, 64);
  float rstd = rsqrtf(vs*(1.0f/384.0f) + 1e-5f);
  short2v* yr = (short2v*)(y + (size_t)row*384);
  const float2* gv = (const float2*)g; const float2* bv = (const float2*)b;
  #pragma unroll
  for (int j=0;j<3;j++){
    float2 gg = gv[l+64*j], bb = bv[l+64*j];
    float o0 = (v[j].x-mean)*rstd*gg.x + bb.x;
    float o1 = (v[j].y-mean)*rstd*gg.y + bb.y;
    if (GELU){ o0 = gelu_f(o0); o1 = gelu_f(o1); }
    short2v pk; pk[0]=bfs(o0); pk[1]=bfs(o1);
    yr[l+64*j] = pk;
  }
}

// ---- LayerNorm with row-conditional source: cls rows (row%50==0) from xa, else xbse
__global__ __launch_bounds__(256) void ln_sel_kernel(const float* __restrict__ xa,
    const float* __restrict__ xbse,
    const float* __restrict__ g, const float* __restrict__ b,
    bf16* __restrict__ y, int rows)
{
  int row = blockIdx.x*4 + (threadIdx.x>>6);
  if (row >= rows) return;
  int l = threadIdx.x & 63;
  const float* src = (row % 50 == 0) ? xa : xbse;
  const float2* xr = (const float2*)(src + (size_t)row*384);
  float2 v[3]; float s = 0.f;
  #pragma unroll
  for (int j=0;j<3;j++){ v[j] = xr[l + 64*j]; s += v[j].x + v[j].y; }
  #pragma unroll
  for (int off=32; off; off>>=1) s += __shfl_xor(s, off, 64);
  float mean = s * (1.0f/384.0f);
  float vs = 0.f;
  #pragma unroll
  for (int j=0;j<3;j++){ float dx=v[j].x-mean, dy=v[j].y-mean; vs += dx*dx+dy*dy; }
  #pragma unroll
  for (int off=32; off; off>>=1) vs += __shfl_xor(vs, off, 64);
  float rstd = rsqrtf(vs*(1.0f/384.0f) + 1e-5f);
  short2v* yr = (short2v*)(y + (size_t)row*384);
  const float2* gv = (const float2*)g; const float2* bv = (const float2*)b;
  #pragma unroll
  for (int j=0;j<3;j++){
    float2 gg = gv[l+64*j], bb = bv[l+64*j];
    short2v pk;
    pk[0]=bfs((v[j].x-mean)*rstd*gg.x + bb.x);
    pk[1]=bfs((v[j].y-mean)*rstd*gg.y + bb.y);
    yr[l+64*j] = pk;
  }
}

// ------- dual LayerNorm: one read, two outputs (expand-gelu @lde, mlp @384) -------
__global__ __launch_bounds__(256) void ln_dual_kernel(const float* __restrict__ x,
    const float* __restrict__ ge, const float* __restrict__ be,
    const float* __restrict__ g2, const float* __restrict__ b2,
    bf16* __restrict__ yeo, long lde, bf16* __restrict__ y2o, int rows)
{
  int row = blockIdx.x*4 + (threadIdx.x>>6);
  if (row >= rows) return;
  int l = threadIdx.x & 63;
  const float2* xr = (const float2*)(x + (size_t)row*384);
  float2 v[3]; float s = 0.f;
  #pragma unroll
  for (int j=0;j<3;j++){ v[j] = xr[l + 64*j]; s += v[j].x + v[j].y; }
  #pragma unroll
  for (int off=32; off; off>>=1) s += __shfl_xor(s, off, 64);
  float mean = s * (1.0f/384.0f);
  float vs = 0.f;
  #pragma unroll
  for (int j=0;j<3;j++){ float dx=v[j].x-mean, dy=v[j].y-mean; vs += dx*dx+dy*dy; }
  #pragma unroll
  for (int off=32; off; off>>=1) vs += __shfl_xor(vs, off, 64);
  float rstd = rsqrtf(vs*(1.0f/384.0f) + 1e-5f);
  short2v* ye = (short2v*)(yeo + (size_t)row*lde);
  short2v* y2 = (short2v*)(y2o + (size_t)row*384);
  const float2* gev = (const float2*)ge; const float2* bev = (const float2*)be;
  const float2* g2v = (const float2*)g2; const float2* b2v = (const float2*)b2;
  #pragma unroll
  for (int j=0;j<3;j++){
    float n0 = (v[j].x-mean)*rstd, n1 = (v[j].y-mean)*rstd;
    float2 gg = gev[l+64*j], bb = bev[l+64*j];
    short2v pe; pe[0]=bfs(gelu_f(n0*gg.x+bb.x)); pe[1]=bfs(gelu_f(n1*gg.y+bb.y));
    ye[l+64*j] = pe;
    gg = g2v[l+64*j]; bb = b2v[l+64*j];
    short2v p2; p2[0]=bfs(n0*gg.x+bb.x); p2[1]=bfs(n1*gg.y+bb.y);
    y2[l+64*j] = p2;
  }
}

// ---------------- GEMM: C[M,N] = A[M,K](bf16, lda) * B[N,K]^T (ldb), fp32 acc -----
// 128x128 tile, 4 waves, depth-2 prefetch (3 LDS buffers, counted vmcnt(4)),
// XCD-bijective swizzle. [proven]  GELU: 0=none 1=sigmoid-fast
// RES: 0=none 1=fp32  3=row-conditional fp32 (cls row%50==0 -> res, else res2)
template<bool OUT_BF16, bool BIAS, int RES, int GELU>
__device__ __forceinline__ void gemm_dev(
    const bf16* __restrict__ A, const bf16* __restrict__ B, void* Cv,
    const float* __restrict__ bias, const void* res, const void* res2,
    int M, int N, int K, int lda, int ldb, int ldc, int ldres)
{
  __shared__ short As[3][128*32];
  __shared__ short Bs[3][128*32];
  const int t  = threadIdx.x;
  const int l  = t & 63;
  const int w  = t >> 6;
  const int wr = w >> 1, wc = w & 1;
  const int lr = l & 15, kg = l >> 4;

  const int nwg = gridDim.x * gridDim.y;
  const int lin = blockIdx.y * gridDim.x + blockIdx.x;
  const int q8 = nwg >> 3, r8 = nwg & 7;
  const int xcd = lin & 7, slot = lin >> 3;
  const int swz = (xcd < r8) ? (xcd*(q8+1) + slot) : (r8*(q8+1) + (xcd-r8)*q8 + slot);
  const int by = swz / gridDim.x, bx = swz - by*gridDim.x;

  const int bm = by * 128, bn = bx * 128;
  const short* Ag = (const short*)A;
  const short* Bg = (const short*)B;

  const int eo0 = w*1024 + l*8;
  const int rowS0 = eo0 >> 5, colS0 = eo0 & 31;
  const int eo1 = eo0 + 512;
  const int rowS1 = eo1 >> 5, colS1 = eo1 & 31;

  #define STAGE(k0, b) do { \
    __builtin_amdgcn_global_load_lds( \
      (const __attribute__((address_space(1))) void*)&Ag[(size_t)(bm+rowS0)*lda + (k0) + colS0], \
      (__attribute__((address_space(3))) void*)((char*)&As[b][0] + w*2048), 16, 0, 0); \
    __builtin_amdgcn_global_load_lds( \
      (const __attribute__((address_space(1))) void*)&Bg[(size_t)(bn+rowS0)*ldb + (k0) + colS0], \
      (__attribute__((address_space(3))) void*)((char*)&Bs[b][0] + w*2048), 16, 0, 0); \
    __builtin_amdgcn_global_load_lds( \
      (const __attribute__((address_space(1))) void*)&Ag[(size_t)(bm+rowS1)*lda + (k0) + colS1], \
      (__attribute__((address_space(3))) void*)((char*)&As[b][0] + w*2048 + 1024), 16, 0, 0); \
    __builtin_amdgcn_global_load_lds( \
      (const __attribute__((address_space(1))) void*)&Bg[(size_t)(bn+rowS1)*ldb + (k0) + colS1], \
      (__attribute__((address_space(3))) void*)((char*)&Bs[b][0] + w*2048 + 1024), 16, 0, 0); \
  } while(0)

  f32x4 acc[4][4] = {};

  STAGE(0, 0);
  STAGE(32, 1);
  asm volatile("s_waitcnt vmcnt(4)" ::: "memory");
  __builtin_amdgcn_s_barrier();

  int cur = 0, nb = 2;
  for (int k0 = 0; k0 < K; k0 += 32) {
    const bool more = (k0 + 64 < K);
    if (more) STAGE(k0 + 64, nb);

    short8 af[4], bfm[4];
    #pragma unroll
    for (int m=0;m<4;m++) af[m]  = *(const short8*)(&As[cur][(wr*64 + m*16 + lr)*32 + kg*8]);
    #pragma unroll
    for (int n=0;n<4;n++) bfm[n] = *(const short8*)(&Bs[cur][(wc*64 + n*16 + lr)*32 + kg*8]);
    __builtin_amdgcn_s_setprio(1);
    #pragma unroll
    for (int m=0;m<4;m++)
      #pragma unroll
      for (int n=0;n<4;n++)
        acc[m][n] = __builtin_amdgcn_mfma_f32_16x16x32_bf16(af[m], bfm[n], acc[m][n], 0,0,0);
    __builtin_amdgcn_s_setprio(0);

    if (more) { asm volatile("s_waitcnt vmcnt(4)" ::: "memory"); }
    else      { asm volatile("s_waitcnt vmcnt(0)" ::: "memory"); }
    __builtin_amdgcn_s_barrier();
    cur = (cur==2) ? 0 : cur+1;
    nb  = (nb==2)  ? 0 : nb+1;
  }
  #undef STAGE

  #pragma unroll
  for (int m=0;m<4;m++){
    int row0 = bm + wr*64 + m*16 + kg*4;
    #pragma unroll
    for (int n=0;n<4;n++){
      int col = bn + wc*64 + n*16 + lr;
      float bv = BIAS ? bias[col] : 0.0f;
      #pragma unroll
      for (int r=0;r<4;r++){
        float val = acc[m][n][r] + bv;
        if (RES == 1) val += ((const float*)res)[(size_t)(row0+r)*ldres + col];
        if (RES == 3){
          int grow = row0 + r;
          const float* rs = ((grow % 50) == 0) ? (const float*)res : (const float*)res2;
          val += rs[(size_t)grow*ldres + col];
        }
        if (GELU == 1) val = gelu_fast(val);
        if (OUT_BF16) ((bf16*)Cv)[(size_t)(row0+r)*ldc + col] = __float2bfloat16(val);
        else          ((float*)Cv)[(size_t)(row0+r)*ldc + col] = val;
      }
    }
  }
}

#define GEMM_K(NAME, OB, BI, RE, GE) \
__global__ __launch_bounds__(256) void NAME( \
    const bf16* __restrict__ A, const bf16* __restrict__ B, void* Cv, \
    const float* __restrict__ bias, const void* res, const void* res2, \
    int M, int N, int K, int lda, int ldc, int ldres){ \
  gemm_dev<OB,BI,RE,GE>(A,B,Cv,bias,res,res2,M,N,K,lda,K,ldc,ldres); }

GEMM_K(gemm_qkv_k,   true,  false, 0, 0)   // qkv: bf16 out
GEMM_K(gemm_projc_k, false, true,  1, 0)   // cls proj: +bias, +fp32 res, fp32 out
GEMM_K(gemm_projw_k, false, true,  3, 0)   // window proj: row-conditional residual
GEMM_K(gemm_fc1_k,   true,  true,  0, 1)   // fc1: +bias, fast-gelu, bf16 out (ldc=KTAIL)
GEMM_K(gemm_tail_k,  false, true,  0, 0)   // fused tail: +bias_c, fp32 out (dout)
GEMM_K(gemm_wcmb_k,  true,  false, 0, 0)   // weight-combo precompute, bf16 out

// ---------------- cls attention (small; unchanged) ----------------
__global__ __launch_bounds__(256) void attn_cls_kernel(const bf16* __restrict__ qkv,
                                                       bf16* __restrict__ y)
{
  int img = blockIdx.x, h = blockIdx.y;
  __shared__ float q[64][33], k[64][33], v[64][33];
  __shared__ float s[64][65];
  int t = threadIdx.x;
  for (int idx=t; idx<64*32; idx+=256){
    int i = idx>>5, d = idx&31;
    const bf16* base = qkv + ((size_t)(img*64+i))*QKVD + h*32 + d;
    q[i][d] = __bfloat162float(base[0]);
    k[i][d] = __bfloat162float(base[384]);
    v[i][d] = __bfloat162float(base[768]);
  }
  __syncthreads();
  for (int idx=t; idx<64*64; idx+=256){
    int i = idx>>6, j = idx&63;
    float a = 0.f;
    #pragma unroll
    for (int d=0; d<32; d++) a += q[i][d]*k[j][d];
    s[i][j] = a * SCALE_F;
  }
  __syncthreads();
  if (t < 64){
    float m = -1e30f;
    for (int j=0;j<64;j++) m = fmaxf(m, s[t][j]);
    float sum = 0.f;
    for (int j=0;j<64;j++){ float e = __expf(s[t][j]-m); s[t][j]=e; sum+=e; }
    float inv = rcp_fast(sum);
    for (int j=0;j<64;j++) s[t][j] *= inv;
  }
  __syncthreads();
  for (int idx=t; idx<64*32; idx+=256){
    int i = idx>>5, d = idx&31;
    float a = 0.f;
    for (int j=0;j<64;j++) a += s[i][j]*v[j][d];
    y[((size_t)(img*64+i))*CDIM + h*32 + d] = __float2bfloat16(a);
  }
}

// ======== MFMA window attention (proven round-8) ========
__global__ __launch_bounds__(64) void attn_win_mfma(const bf16* __restrict__ qkv,
    const float* __restrict__ mask, const float* __restrict__ rel_pos,
    bf16* __restrict__ y)
{
  const int lw = blockIdx.x, h = blockIdx.y;
  const int l = threadIdx.x;
  const int lr = l & 15, kg = l >> 4;
  __shared__ short Plds[64*72];
  __shared__ short VTl[32*72];
  __shared__ float rp[169];

  const size_t tok0 = (size_t)lw * NTOK;
  const short* qbase = (const short*)qkv;

  for (int i=l; i<169; i+=64) rp[i] = rel_pos[i*NHEADS + h];

  short8 qf[4], kf[4];
  #pragma unroll
  for (int n=0;n<4;n++){
    int qt = 16*n + lr;
    if (qt < 50) qf[n] = *(const short8*)&qbase[(tok0+qt)*QKVD + h*32 + kg*8];
    else         qf[n] = short8(0);
  }
  #pragma unroll
  for (int m=0;m<4;m++){
    int kt = 16*m + lr;
    if (kt < 50) kf[m] = *(const short8*)&qbase[(tok0+kt)*QKVD + 384 + h*32 + kg*8];
    else         kf[m] = short8(0);
  }

  {
    short vv[32];
    if (l < 50){
      const short8* vp = (const short8*)&qbase[(tok0+l)*QKVD + 768 + h*32];
      #pragma unroll
      for (int jj=0;jj<4;jj++){ short8 xv = vp[jj];
        #pragma unroll
        for (int e=0;e<8;e++) vv[jj*8+e] = xv[e]; }
    } else {
      #pragma unroll
      for (int d=0; d<32; d++) vv[d]=0;
    }
    #pragma unroll
    for (int d=0; d<32; d++) VTl[d*72 + l] = vv[d];
  }

  f32x4 sacc[4][4] = {};
  #pragma unroll
  for (int m=0;m<4;m++)
    #pragma unroll
    for (int n=0;n<4;n++)
      sacc[m][n] = __builtin_amdgcn_mfma_f32_16x16x32_bf16(kf[m], qf[n], sacc[m][n], 0,0,0);

  const float* mrow = mask + (size_t)lw*2500;
  float sv[4][4][4];
  #pragma unroll
  for (int m=0;m<4;m++){
    #pragma unroll
    for (int r=0;r<4;r++){
      int kt = 16*m + 4*kg + r;
      #pragma unroll
      for (int n=0;n<4;n++){
        int qt = 16*n + lr;
        float a;
        if (kt < 50 && qt < 50){
          a = sacc[m][n][r] * SCALE_F;
          if (kt>=1 && qt>=1){
            int qi=qt-1, kj=kt-1;
            int ridx = ((qi/7)-(kj/7)+6)*13 + (qi%7)-(kj%7)+6;
            a += rp[ridx];
          }
          a += mrow[qt*50+kt];
        } else a = -1e30f;
        sv[m][r][n] = a;
      }
    }
  }

  #pragma unroll
  for (int n=0;n<4;n++){
    float mx = -1e30f;
    #pragma unroll
    for (int m=0;m<4;m++)
      #pragma unroll
      for (int r=0;r<4;r++) mx = fmaxf(mx, sv[m][r][n]);
    mx = fmaxf(mx, __shfl_xor(mx, 16));
    mx = fmaxf(mx, __shfl_xor(mx, 32));
    float sum = 0.f;
    float pv[4][4];
    #pragma unroll
    for (int m=0;m<4;m++)
      #pragma unroll
      for (int r=0;r<4;r++){ float p = __expf(sv[m][r][n]-mx); pv[m][r]=p; sum+=p; }
    sum += __shfl_xor(sum, 16);
    sum += __shfl_xor(sum, 32);
    float inv = rcp_fast(sum);
    int qrow = (16*n + lr)*72;
    #pragma unroll
    for (int m=0;m<4;m++){
      short4v pk;
      #pragma unroll
      for (int r=0;r<4;r++) pk[r] = bfs(pv[m][r]*inv);
      *(short4v*)&Plds[qrow + 16*m + 4*kg] = pk;
    }
  }
  __syncthreads();

  f32x4 oacc[2][4] = {};
  #pragma unroll
  for (int ks=0; ks<2; ks++){
    short8 pf[4];
    #pragma unroll
    for (int n=0;n<4;n++)
      pf[n] = *(const short8*)&Plds[(16*n+lr)*72 + 32*ks + kg*8];
    #pragma unroll
    for (int md=0; md<2; md++){
      short8 vf = *(const short8*)&VTl[(16*md+lr)*72 + 32*ks + kg*8];
      #pragma unroll
      for (int n=0;n<4;n++)
        oacc[md][n] = __builtin_amdgcn_mfma_f32_16x16x32_bf16(vf, pf[n], oacc[md][n], 0,0,0);
    }
  }

  short* yb = (short*)y;
  #pragma unroll
  for (int n=0;n<4;n++){
    int qt = 16*n + lr;
    if (qt >= 50) continue;
    #pragma unroll
    for (int md=0; md<2; md++){
      short4v pk;
      #pragma unroll
      for (int r=0;r<4;r++) pk[r] = bfs(oacc[md][n][r]);
      *(short4v*)&yb[(tok0+qt)*CDIM + h*32 + 16*md + 4*kg] = pk;
    }
  }
}

// ---------------------------------------------------------------------------
extern "C" void kernel_launch(void* const* d_in, const int* in_sizes, int n_in,
                              void* d_out, int out_size, void* d_ws, size_t ws_size,
                              hipStream_t stream)
{
  const float* x_in   = (const float*)d_in[0];
  const float* maskp  = (const float*)d_in[1];
  const float* g0 = (const float*)d_in[2];  const float* b0 = (const float*)d_in[3];
  const float* g1 = (const float*)d_in[4];  const float* b1 = (const float*)d_in[5];
  const float* g2 = (const float*)d_in[6];  const float* b2 = (const float*)d_in[7];
  const float* ge = (const float*)d_in[8];  const float* be = (const float*)d_in[9];
  const float* w_qkv = (const float*)d_in[10];
  const float* w_proj= (const float*)d_in[11];
  const float* b_proj= (const float*)d_in[12];
  const float* rel_pos=(const float*)d_in[13];
  const float* w_fc1 = (const float*)d_in[14];
  const float* b_fc1 = (const float*)d_in[15];
  const float* w_fc2 = (const float*)d_in[16];
  const float* b_fc2 = (const float*)d_in[17];
  const float* w_exp = (const float*)d_in[18];
  const float* b_exp = (const float*)d_in[19];
  const float* w_lin = (const float*)d_in[20];
  const float* b_lin = (const float*)d_in[21];
  float* dout = (float*)d_out;

  const size_t NT = (size_t)NWIN * NTOK;

  size_t off = 0;
  auto alloc = [&](size_t bytes)->void* {
    void* p = (char*)d_ws + off;
    off += (bytes + 255) & ~(size_t)255;
    return p;
  };

  bf16* wqkv_b = (bf16*)alloc((size_t)QKVD*CDIM*2);
  bf16* wproj_b= (bf16*)alloc((size_t)CDIM*CDIM*2);
  bf16* wfc1_b = (bf16*)alloc((size_t)MLPH*CDIM*2);
  bf16* wlin_b = (bf16*)alloc((size_t)CDIM*DHID*2);
  bf16* wexpT_b= (bf16*)alloc((size_t)CDIM*DHID*2);   // w_exp^T  [384,768]
  bf16* wfc2T_b= (bf16*)alloc((size_t)MLPH*DHID*2);   // w_fc2^T  [3072,768]
  bf16* W_comb = (bf16*)alloc((size_t)CDIM*KTAIL*2);  // [384][3456] = [W_el | W_h]
  float* biasc = (float*)alloc((size_t)CDIM*4);
  float* xb    = (float*)alloc(NT*CDIM*4);
  bf16* clsln  = (bf16*)alloc((size_t)NWIN*CDIM*2);
  bf16* qkvcls = (bf16*)alloc((size_t)NWIN*QKVD*2);
  bf16* ycls   = (bf16*)alloc((size_t)NWIN*CDIM*2);

  // per-window: xln 38400 + ybfc 38400 + h1ext 345600 = 422400 (qkvc aliases h1ext)
  int CH_W = 2048;
  const size_t per_window = 422400ull;
  while (CH_W > 128 && off + (size_t)CH_W*per_window + 16384 > ws_size) CH_W >>= 1;
  const int CH_T = CH_W * NTOK;

  bf16*  xln   = (bf16*) alloc((size_t)CH_T*CDIM*2);
  bf16*  ybfc  = (bf16*) alloc((size_t)CH_T*CDIM*2);
  bf16*  h1ext = (bf16*) alloc((size_t)CH_T*KTAIL*2);  // [M][3456]: [geluLNe | gelu(fc1)]
  // qkv activations alias the FRONT of h1ext (dead before h1ext is written)
  bf16*  qkvc  = h1ext;

  // ---- precompute ----
  cvt4_kernel<<<512, 256, 0, stream>>>(
      w_qkv, wqkv_b, QKVD*CDIM,  w_proj, wproj_b, CDIM*CDIM,
      w_fc1, wfc1_b, MLPH*CDIM,  w_lin,  wlin_b,  CDIM*DHID);
  transpose_cvt_kernel<<<dim3(CDIM/32, DHID/32), 256, 0, stream>>>(w_exp, wexpT_b, DHID, CDIM);
  transpose_cvt_kernel<<<dim3(MLPH/32, DHID/32), 256, 0, stream>>>(w_fc2, wfc2T_b, DHID, MLPH);
  bias_combine_kernel<<<6, 64, 0, stream>>>(w_lin, b_lin, b_exp, b_fc2, biasc);
  gemm_wcmb_k<<<dim3(CDIM/128, CDIM/128), 256, 0, stream>>>(
      wlin_b, wexpT_b, W_comb, nullptr, nullptr, nullptr, CDIM, CDIM, DHID, DHID, KTAIL, 0);
  gemm_wcmb_k<<<dim3(MLPH/128, CDIM/128), 256, 0, stream>>>(
      wlin_b, wfc2T_b, W_comb + 384, nullptr, nullptr, nullptr, CDIM, MLPH, DHID, DHID, KTAIL, 0);

  // ---- cls path (writes only cls rows of xb; other rows never read) ----
  ln_kernel<false><<<NWIN/4, 256, 0, stream>>>(x_in, (long)NTOK*CDIM, g0, b0, clsln, NWIN);
  gemm_qkv_k<<<dim3(QKVD/128, NWIN/128), 256, 0, stream>>>(
      clsln, wqkv_b, qkvcls, nullptr, nullptr, nullptr, NWIN, QKVD, CDIM, CDIM, QKVD, 0);
  attn_cls_kernel<<<dim3(IMGS, NHEADS), 256, 0, stream>>>(qkvcls, ycls);
  gemm_projc_k<<<dim3(CDIM/128, NWIN/128), 256, 0, stream>>>(
      ycls, wproj_b, xb, b_proj, x_in, nullptr, NWIN, CDIM, CDIM, CDIM, NTOK*CDIM, NTOK*CDIM);

  // ---- main chunk loop ----
  const int nch = NWIN / CH_W;
  for (int c = 0; c < nch; c++){
    int w0 = c * CH_W;
    size_t t0 = (size_t)w0 * NTOK;
    float* xbc = xb + t0*CDIM;
    const float* xinc = x_in + t0*CDIM;
    float* doutc = dout + t0*CDIM;
    int MT = CH_T, MB = CH_T/128;

    ln_sel_kernel<<<MT/4, 256, 0, stream>>>(xbc, xinc, g1, b1, xln, MT);
    gemm_qkv_k<<<dim3(QKVD/128, MB), 256, 0, stream>>>(
        xln, wqkv_b, qkvc, nullptr, nullptr, nullptr, MT, QKVD, CDIM, CDIM, QKVD, 0);
    attn_win_mfma<<<dim3(CH_W, NHEADS), 64, 0, stream>>>(
        qkvc, maskp + (size_t)w0*2500, rel_pos, ybfc);
    gemm_projw_k<<<dim3(CDIM/128, MB), 256, 0, stream>>>(
        ybfc, wproj_b, xbc, b_proj, xbc, xinc, MT, CDIM, CDIM, CDIM, CDIM, CDIM);

    ln_dual_kernel<<<MT/4, 256, 0, stream>>>(xbc, ge, be, g2, b2, h1ext, KTAIL, ybfc, MT);

    gemm_fc1_k<<<dim3(MLPH/128, MB), 256, 0, stream>>>(
        ybfc, wfc1_b, h1ext + 384, b_fc1, nullptr, nullptr, MT, MLPH, CDIM, CDIM, KTAIL, 0);

    gemm_tail_k<<<dim3(CDIM/128, MB), 256, 0, stream>>>(
        h1ext, W_comb, doutc, biasc, nullptr, nullptr, MT, CDIM, KTAIL, KTAIL, CDIM, 0);
  }
}

// Round 17
// 1602.820 us; speedup vs baseline: 1.2181x; 1.0321x over previous
//
#include <hip/hip_runtime.h>
#include <hip/hip_bf16.h>
#include <math.h>

#define NHEADS 12
#define NTOK   50
#define NWIN   2048
#define IMGS   32
#define CDIM   384
#define QKVD   1152
#define DHID   768
#define MLPH   3072
#define KTAIL  3456   // 384 + 3072
#define SCALE_F 0.17677669529663687f

typedef short short8 __attribute__((ext_vector_type(8)));
typedef short short4v __attribute__((ext_vector_type(4)));
typedef short short2v __attribute__((ext_vector_type(2)));
typedef float f32x4  __attribute__((ext_vector_type(4)));
typedef __hip_bfloat16 bf16;

__device__ __forceinline__ float rcp_fast(float x){ return __builtin_amdgcn_rcpf(x); }

// tanh-form gelu (|err| ~1e-3) — LN paths (cold)
__device__ __forceinline__ float gelu_f(float x){
  float z = 0.7978845608028654f*(x + 0.044715f*x*x*x);
  float e = __expf(2.0f*z);
  return 0.5f*x*(1.0f + (1.0f - 2.0f*rcp_fast(e+1.0f)));
}
// sigmoid-form gelu — hot fc1 epilogue
__device__ __forceinline__ float gelu_fast(float x){
  float e = __expf(-1.702f*x);
  return x * rcp_fast(1.0f + e);
}
__device__ __forceinline__ short bfs(float x){
  bf16 h = __float2bfloat16(x); return *(short*)&h;
}

// ---------------- weights fp32 -> bf16 (4 tensors) ----------------
__global__ void cvt4_kernel(const float* s0, bf16* d0, int n0,
                            const float* s1, bf16* d1, int n1,
                            const float* s2, bf16* d2, int n2,
                            const float* s3, bf16* d3, int n3){
  int stride = gridDim.x*blockDim.x, g = blockIdx.x*blockDim.x + threadIdx.x;
  for (int i=g; i<n0; i+=stride) d0[i] = __float2bfloat16(s0[i]);
  for (int i=g; i<n1; i+=stride) d1[i] = __float2bfloat16(s1[i]);
  for (int i=g; i<n2; i+=stride) d2[i] = __float2bfloat16(s2[i]);
  for (int i=g; i<n3; i+=stride) d3[i] = __float2bfloat16(s3[i]);
}

// ---------------- transpose + cvt: src[R][Cc] fp32 -> dst[Cc][R] bf16 ------------
__global__ __launch_bounds__(256) void transpose_cvt_kernel(const float* __restrict__ src,
    bf16* __restrict__ dst, int R, int Cc){
  __shared__ float tile[32][33];
  int bx = blockIdx.x, by = blockIdx.y;
  int c = threadIdx.x & 31, r0 = threadIdx.x >> 5;
  #pragma unroll
  for (int rr = r0; rr < 32; rr += 8)
    tile[rr][c] = src[(size_t)(by*32+rr)*Cc + bx*32 + c];
  __syncthreads();
  #pragma unroll
  for (int rr = r0; rr < 32; rr += 8)
    dst[(size_t)(bx*32+rr)*R + by*32 + c] = __float2bfloat16(tile[c][rr]);
}

// ---------------- bias_c = b_lin + w_lin * (b_exp + b_fc2) ----------------
__global__ void bias_combine_kernel(const float* __restrict__ wlin,
    const float* __restrict__ b_lin, const float* __restrict__ b_exp,
    const float* __restrict__ b_fc2, float* __restrict__ biasc){
  int i = blockIdx.x*blockDim.x + threadIdx.x;
  if (i >= CDIM) return;
  float s = b_lin[i];
  for (int d=0; d<DHID; d++) s += wlin[(size_t)i*DHID+d]*(b_exp[d]+b_fc2[d]);
  biasc[i] = s;
}

// ---------------- LayerNorm, fp32 in -> bf16 out ----------------
template<bool GELU>
__global__ __launch_bounds__(256) void ln_kernel(const float* __restrict__ x, long ldx,
    const float* __restrict__ g, const float* __restrict__ b,
    bf16* __restrict__ y, int rows)
{
  int row = blockIdx.x*4 + (threadIdx.x>>6);
  if (row >= rows) return;
  int l = threadIdx.x & 63;
  const float2* xr = (const float2*)(x + (size_t)row*ldx);
  float2 v[3]; float s = 0.f;
  #pragma unroll
  for (int j=0;j<3;j++){ v[j] = xr[l + 64*j]; s += v[j].x + v[j].y; }
  #pragma unroll
  for (int off=32; off; off>>=1) s += __shfl_xor(s, off, 64);
  float mean = s * (1.0f/384.0f);
  float vs = 0.f;
  #pragma unroll
  for (int j=0;j<3;j++){ float dx=v[j].x-mean, dy=v[j].y-mean; vs += dx*dx+dy*dy; }
  #pragma unroll
  for (int off=32; off; off>>=1) vs += __shfl_xor(vs, off, 64);
  float rstd = rsqrtf(vs*(1.0f/384.0f) + 1e-5f);
  short2v* yr = (short2v*)(y + (size_t)row*384);
  const float2* gv = (const float2*)g; const float2* bv = (const float2*)b;
  #pragma unroll
  for (int j=0;j<3;j++){
    float2 gg = gv[l+64*j], bb = bv[l+64*j];
    float o0 = (v[j].x-mean)*rstd*gg.x + bb.x;
    float o1 = (v[j].y-mean)*rstd*gg.y + bb.y;
    if (GELU){ o0 = gelu_f(o0); o1 = gelu_f(o1); }
    short2v pk; pk[0]=bfs(o0); pk[1]=bfs(o1);
    yr[l+64*j] = pk;
  }
}

// ---- LayerNorm with row-conditional source: cls rows (row%50==0) from xa, else xbse
__global__ __launch_bounds__(256) void ln_sel_kernel(const float* __restrict__ xa,
    const float* __restrict__ xbse,
    const float* __restrict__ g, const float* __restrict__ b,
    bf16* __restrict__ y, int rows)
{
  int row = blockIdx.x*4 + (threadIdx.x>>6);
  if (row >= rows) return;
  int l = threadIdx.x & 63;
  const float* src = (row % 50 == 0) ? xa : xbse;
  const float2* xr = (const float2*)(src + (size_t)row*384);
  float2 v[3]; float s = 0.f;
  #pragma unroll
  for (int j=0;j<3;j++){ v[j] = xr[l + 64*j]; s += v[j].x + v[j].y; }
  #pragma unroll
  for (int off=32; off; off>>=1) s += __shfl_xor(s, off, 64);
  float mean = s * (1.0f/384.0f);
  float vs = 0.f;
  #pragma unroll
  for (int j=0;j<3;j++){ float dx=v[j].x-mean, dy=v[j].y-mean; vs += dx*dx+dy*dy; }
  #pragma unroll
  for (int off=32; off; off>>=1) vs += __shfl_xor(vs, off, 64);
  float rstd = rsqrtf(vs*(1.0f/384.0f) + 1e-5f);
  short2v* yr = (short2v*)(y + (size_t)row*384);
  const float2* gv = (const float2*)g; const float2* bv = (const float2*)b;
  #pragma unroll
  for (int j=0;j<3;j++){
    float2 gg = gv[l+64*j], bb = bv[l+64*j];
    short2v pk;
    pk[0]=bfs((v[j].x-mean)*rstd*gg.x + bb.x);
    pk[1]=bfs((v[j].y-mean)*rstd*gg.y + bb.y);
    yr[l+64*j] = pk;
  }
}

// ------- dual LayerNorm: one read, two outputs (expand-gelu @lde, mlp @384) -------
__global__ __launch_bounds__(256) void ln_dual_kernel(const float* __restrict__ x,
    const float* __restrict__ ge, const float* __restrict__ be,
    const float* __restrict__ g2, const float* __restrict__ b2,
    bf16* __restrict__ yeo, long lde, bf16* __restrict__ y2o, int rows)
{
  int row = blockIdx.x*4 + (threadIdx.x>>6);
  if (row >= rows) return;
  int l = threadIdx.x & 63;
  const float2* xr = (const float2*)(x + (size_t)row*384);
  float2 v[3]; float s = 0.f;
  #pragma unroll
  for (int j=0;j<3;j++){ v[j] = xr[l + 64*j]; s += v[j].x + v[j].y; }
  #pragma unroll
  for (int off=32; off; off>>=1) s += __shfl_xor(s, off, 64);
  float mean = s * (1.0f/384.0f);
  float vs = 0.f;
  #pragma unroll
  for (int j=0;j<3;j++){ float dx=v[j].x-mean, dy=v[j].y-mean; vs += dx*dx+dy*dy; }
  #pragma unroll
  for (int off=32; off; off>>=1) vs += __shfl_xor(vs, off, 64);
  float rstd = rsqrtf(vs*(1.0f/384.0f) + 1e-5f);
  short2v* ye = (short2v*)(yeo + (size_t)row*lde);
  short2v* y2 = (short2v*)(y2o + (size_t)row*384);
  const float2* gev = (const float2*)ge; const float2* bev = (const float2*)be;
  const float2* g2v = (const float2*)g2; const float2* b2v = (const float2*)b2;
  #pragma unroll
  for (int j=0;j<3;j++){
    float n0 = (v[j].x-mean)*rstd, n1 = (v[j].y-mean)*rstd;
    float2 gg = gev[l+64*j], bb = bev[l+64*j];
    short2v pe; pe[0]=bfs(gelu_f(n0*gg.x+bb.x)); pe[1]=bfs(gelu_f(n1*gg.y+bb.y));
    ye[l+64*j] = pe;
    gg = g2v[l+64*j]; bb = b2v[l+64*j];
    short2v p2; p2[0]=bfs(n0*gg.x+bb.x); p2[1]=bfs(n1*gg.y+bb.y);
    y2[l+64*j] = p2;
  }
}

// ---------------- GEMM: C[M,N] = A[M,K](bf16, lda) * B[N,K]^T (ldb), fp32 acc -----
// 128x128 tile, 4 waves, depth-2 prefetch (3 LDS buffers, counted vmcnt(4)),
// XCD-bijective swizzle. [proven]  GELU: 0=none 1=sigmoid-fast
// RES: 0=none 1=fp32  3=row-conditional fp32 (cls row%50==0 -> res, else res2)
template<bool OUT_BF16, bool BIAS, int RES, int GELU>
__device__ __forceinline__ void gemm_dev(
    const bf16* __restrict__ A, const bf16* __restrict__ B, void* Cv,
    const float* __restrict__ bias, const void* res, const void* res2,
    int M, int N, int K, int lda, int ldb, int ldc, int ldres)
{
  __shared__ short As[3][128*32];
  __shared__ short Bs[3][128*32];
  const int t  = threadIdx.x;
  const int l  = t & 63;
  const int w  = t >> 6;
  const int wr = w >> 1, wc = w & 1;
  const int lr = l & 15, kg = l >> 4;

  const int nwg = gridDim.x * gridDim.y;
  const int lin = blockIdx.y * gridDim.x + blockIdx.x;
  const int q8 = nwg >> 3, r8 = nwg & 7;
  const int xcd = lin & 7, slot = lin >> 3;
  const int swz = (xcd < r8) ? (xcd*(q8+1) + slot) : (r8*(q8+1) + (xcd-r8)*q8 + slot);
  const int by = swz / gridDim.x, bx = swz - by*gridDim.x;

  const int bm = by * 128, bn = bx * 128;
  const short* Ag = (const short*)A;
  const short* Bg = (const short*)B;

  const int eo0 = w*1024 + l*8;
  const int rowS0 = eo0 >> 5, colS0 = eo0 & 31;
  const int eo1 = eo0 + 512;
  const int rowS1 = eo1 >> 5, colS1 = eo1 & 31;

  #define STAGE(k0, b) do { \
    __builtin_amdgcn_global_load_lds( \
      (const __attribute__((address_space(1))) void*)&Ag[(size_t)(bm+rowS0)*lda + (k0) + colS0], \
      (__attribute__((address_space(3))) void*)((char*)&As[b][0] + w*2048), 16, 0, 0); \
    __builtin_amdgcn_global_load_lds( \
      (const __attribute__((address_space(1))) void*)&Bg[(size_t)(bn+rowS0)*ldb + (k0) + colS0], \
      (__attribute__((address_space(3))) void*)((char*)&Bs[b][0] + w*2048), 16, 0, 0); \
    __builtin_amdgcn_global_load_lds( \
      (const __attribute__((address_space(1))) void*)&Ag[(size_t)(bm+rowS1)*lda + (k0) + colS1], \
      (__attribute__((address_space(3))) void*)((char*)&As[b][0] + w*2048 + 1024), 16, 0, 0); \
    __builtin_amdgcn_global_load_lds( \
      (const __attribute__((address_space(1))) void*)&Bg[(size_t)(bn+rowS1)*ldb + (k0) + colS1], \
      (__attribute__((address_space(3))) void*)((char*)&Bs[b][0] + w*2048 + 1024), 16, 0, 0); \
  } while(0)

  f32x4 acc[4][4] = {};

  STAGE(0, 0);
  STAGE(32, 1);
  asm volatile("s_waitcnt vmcnt(4)" ::: "memory");
  __builtin_amdgcn_s_barrier();

  int cur = 0, nb = 2;
  for (int k0 = 0; k0 < K; k0 += 32) {
    const bool more = (k0 + 64 < K);
    if (more) STAGE(k0 + 64, nb);

    short8 af[4], bfm[4];
    #pragma unroll
    for (int m=0;m<4;m++) af[m]  = *(const short8*)(&As[cur][(wr*64 + m*16 + lr)*32 + kg*8]);
    #pragma unroll
    for (int n=0;n<4;n++) bfm[n] = *(const short8*)(&Bs[cur][(wc*64 + n*16 + lr)*32 + kg*8]);
    __builtin_amdgcn_s_setprio(1);
    #pragma unroll
    for (int m=0;m<4;m++)
      #pragma unroll
      for (int n=0;n<4;n++)
        acc[m][n] = __builtin_amdgcn_mfma_f32_16x16x32_bf16(af[m], bfm[n], acc[m][n], 0,0,0);
    __builtin_amdgcn_s_setprio(0);

    if (more) { asm volatile("s_waitcnt vmcnt(4)" ::: "memory"); }
    else      { asm volatile("s_waitcnt vmcnt(0)" ::: "memory"); }
    __builtin_amdgcn_s_barrier();
    cur = (cur==2) ? 0 : cur+1;
    nb  = (nb==2)  ? 0 : nb+1;
  }
  #undef STAGE

  #pragma unroll
  for (int m=0;m<4;m++){
    int row0 = bm + wr*64 + m*16 + kg*4;
    #pragma unroll
    for (int n=0;n<4;n++){
      int col = bn + wc*64 + n*16 + lr;
      float bv = BIAS ? bias[col] : 0.0f;
      #pragma unroll
      for (int r=0;r<4;r++){
        float val = acc[m][n][r] + bv;
        if (RES == 1) val += ((const float*)res)[(size_t)(row0+r)*ldres + col];
        if (RES == 3){
          int grow = row0 + r;
          const float* rs = ((grow % 50) == 0) ? (const float*)res : (const float*)res2;
          val += rs[(size_t)grow*ldres + col];
        }
        if (GELU == 1) val = gelu_fast(val);
        if (OUT_BF16) ((bf16*)Cv)[(size_t)(row0+r)*ldc + col] = __float2bfloat16(val);
        else          ((float*)Cv)[(size_t)(row0+r)*ldc + col] = val;
      }
    }
  }
}

#define GEMM_K(NAME, OB, BI, RE, GE) \
__global__ __launch_bounds__(256) void NAME( \
    const bf16* __restrict__ A, const bf16* __restrict__ B, void* Cv, \
    const float* __restrict__ bias, const void* res, const void* res2, \
    int M, int N, int K, int lda, int ldc, int ldres){ \
  gemm_dev<OB,BI,RE,GE>(A,B,Cv,bias,res,res2,M,N,K,lda,K,ldc,ldres); }

GEMM_K(gemm_qkv_k,   true,  false, 0, 0)   // qkv: bf16 out
GEMM_K(gemm_projc_k, false, true,  1, 0)   // cls proj: +bias, +fp32 res, fp32 out
GEMM_K(gemm_projw_k, false, true,  3, 0)   // window proj: row-conditional residual
GEMM_K(gemm_fc1_k,   true,  true,  0, 1)   // fc1: +bias, fast-gelu, bf16 out (ldc=KTAIL)
GEMM_K(gemm_wcmb_k,  true,  false, 0, 0)   // weight-combo precompute, bf16 out

// tail keeps explicit ldb=KTAIL plumbing (A lda=KTAIL, B=W_comb ldb=KTAIL)
__global__ __launch_bounds__(256) void gemm_tail_k(
    const bf16* __restrict__ A, const bf16* __restrict__ B, void* Cv,
    const float* __restrict__ bias, const void* res, const void* res2,
    int M, int N, int K, int lda, int ldc, int ldres){
  gemm_dev<false,true,0,0>(A,B,Cv,bias,res,res2,M,N,K,lda,KTAIL,ldc,ldres);
}

// ---------------- cls attention (small; unchanged) ----------------
__global__ __launch_bounds__(256) void attn_cls_kernel(const bf16* __restrict__ qkv,
                                                       bf16* __restrict__ y)
{
  int img = blockIdx.x, h = blockIdx.y;
  __shared__ float q[64][33], k[64][33], v[64][33];
  __shared__ float s[64][65];
  int t = threadIdx.x;
  for (int idx=t; idx<64*32; idx+=256){
    int i = idx>>5, d = idx&31;
    const bf16* base = qkv + ((size_t)(img*64+i))*QKVD + h*32 + d;
    q[i][d] = __bfloat162float(base[0]);
    k[i][d] = __bfloat162float(base[384]);
    v[i][d] = __bfloat162float(base[768]);
  }
  __syncthreads();
  for (int idx=t; idx<64*64; idx+=256){
    int i = idx>>6, j = idx&63;
    float a = 0.f;
    #pragma unroll
    for (int d=0; d<32; d++) a += q[i][d]*k[j][d];
    s[i][j] = a * SCALE_F;
  }
  __syncthreads();
  if (t < 64){
    float m = -1e30f;
    for (int j=0;j<64;j++) m = fmaxf(m, s[t][j]);
    float sum = 0.f;
    for (int j=0;j<64;j++){ float e = __expf(s[t][j]-m); s[t][j]=e; sum+=e; }
    float inv = rcp_fast(sum);
    for (int j=0;j<64;j++) s[t][j] *= inv;
  }
  __syncthreads();
  for (int idx=t; idx<64*32; idx+=256){
    int i = idx>>5, d = idx&31;
    float a = 0.f;
    for (int j=0;j<64;j++) a += s[i][j]*v[j][d];
    y[((size_t)(img*64+i))*CDIM + h*32 + d] = __float2bfloat16(a);
  }
}

// ======== MFMA window attention, head-batched: 1 block (2 waves) per window ========
// Wave w handles heads w*6 .. w*6+5 sequentially. Mask staged to LDS once per
// window (was 12x global re-read). All loop LDS regions are per-wave -> no
// barriers in the head loop (same-wave, same-array DS ordering).
__global__ __launch_bounds__(128) void attn_win_mfma(const bf16* __restrict__ qkv,
    const float* __restrict__ mask, const float* __restrict__ rel_pos,
    bf16* __restrict__ y)
{
  const int lw = blockIdx.x;
  const int tid = threadIdx.x;
  const int w = tid >> 6;
  const int l = tid & 63;
  const int lr = l & 15, kg = l >> 4;

  __shared__ float msk[2500];          // 10000 B, shared by both waves (12 heads)
  __shared__ float rp_w[2][169];       // per-wave rel-pos slice
  __shared__ short PldsA[2][64*72];    // per-wave P
  __shared__ short VTlA[2][32*72];     // per-wave V^T

  const size_t tok0 = (size_t)lw * NTOK;
  const short* qbase = (const short*)qkv;

  for (int i = tid; i < 2500; i += 128) msk[i] = mask[(size_t)lw*2500 + i];
  __syncthreads();

  short* Plds = &PldsA[w][0];
  short* VTl  = &VTlA[w][0];
  float* rp   = &rp_w[w][0];

  for (int hh = 0; hh < 6; hh++){
    const int h = w*6 + hh;

    // rel-pos for this head (per-wave region; same-wave write->read ordered)
    for (int i = l; i < 169; i += 64) rp[i] = rel_pos[i*NHEADS + h];

    // Q,K fragments
    short8 qf[4], kf[4];
    #pragma unroll
    for (int n=0;n<4;n++){
      int qt = 16*n + lr;
      if (qt < 50) qf[n] = *(const short8*)&qbase[(tok0+qt)*QKVD + h*32 + kg*8];
      else         qf[n] = short8(0);
    }
    #pragma unroll
    for (int m=0;m<4;m++){
      int kt = 16*m + lr;
      if (kt < 50) kf[m] = *(const short8*)&qbase[(tok0+kt)*QKVD + 384 + h*32 + kg*8];
      else         kf[m] = short8(0);
    }

    // stage V transposed: lane l owns token kt=l
    {
      short vv[32];
      if (l < 50){
        const short8* vp = (const short8*)&qbase[(tok0+l)*QKVD + 768 + h*32];
        #pragma unroll
        for (int jj=0;jj<4;jj++){ short8 xv = vp[jj];
          #pragma unroll
          for (int e=0;e<8;e++) vv[jj*8+e] = xv[e]; }
      } else {
        #pragma unroll
        for (int d=0; d<32; d++) vv[d]=0;
      }
      #pragma unroll
      for (int d=0; d<32; d++) VTl[d*72 + l] = vv[d];
    }

    // QK^T (S^T layout: kt from A-frag rows, qt from B-frag rows)
    f32x4 sacc[4][4] = {};
    #pragma unroll
    for (int m=0;m<4;m++)
      #pragma unroll
      for (int n=0;n<4;n++)
        sacc[m][n] = __builtin_amdgcn_mfma_f32_16x16x32_bf16(kf[m], qf[n], sacc[m][n], 0,0,0);

    // scale + rel-pos + mask (both from LDS); invalid -> -inf
    float sv[4][4][4];
    #pragma unroll
    for (int m=0;m<4;m++){
      #pragma unroll
      for (int r=0;r<4;r++){
        int kt = 16*m + 4*kg + r;
        #pragma unroll
        for (int n=0;n<4;n++){
          int qt = 16*n + lr;
          float a;
          if (kt < 50 && qt < 50){
            a = sacc[m][n][r] * SCALE_F;
            if (kt>=1 && qt>=1){
              int qi=qt-1, kj=kt-1;
              int ridx = ((qi/7)-(kj/7)+6)*13 + (qi%7)-(kj%7)+6;
              a += rp[ridx];
            }
            a += msk[qt*50+kt];
          } else a = -1e30f;
          sv[m][r][n] = a;
        }
      }
    }

    // per-qt softmax over kt; write P (bf16) to per-wave LDS [qt][kt]
    #pragma unroll
    for (int n=0;n<4;n++){
      float mx = -1e30f;
      #pragma unroll
      for (int m=0;m<4;m++)
        #pragma unroll
        for (int r=0;r<4;r++) mx = fmaxf(mx, sv[m][r][n]);
      mx = fmaxf(mx, __shfl_xor(mx, 16));
      mx = fmaxf(mx, __shfl_xor(mx, 32));
      float sum = 0.f;
      float pv[4][4];
      #pragma unroll
      for (int m=0;m<4;m++)
        #pragma unroll
        for (int r=0;r<4;r++){ float p = __expf(sv[m][r][n]-mx); pv[m][r]=p; sum+=p; }
      sum += __shfl_xor(sum, 16);
      sum += __shfl_xor(sum, 32);
      float inv = rcp_fast(sum);
      int qrow = (16*n + lr)*72;
      #pragma unroll
      for (int m=0;m<4;m++){
        short4v pk;
        #pragma unroll
        for (int r=0;r<4;r++) pk[r] = bfs(pv[m][r]*inv);
        *(short4v*)&Plds[qrow + 16*m + 4*kg] = pk;
      }
    }

    // PV: O^T = mfma(A=V^T, B=P), 2 K-steps over kt (same-wave LDS deps ordered)
    f32x4 oacc[2][4] = {};
    #pragma unroll
    for (int ks=0; ks<2; ks++){
      short8 pf[4];
      #pragma unroll
      for (int n=0;n<4;n++)
        pf[n] = *(const short8*)&Plds[(16*n+lr)*72 + 32*ks + kg*8];
      #pragma unroll
      for (int md=0; md<2; md++){
        short8 vf = *(const short8*)&VTl[(16*md+lr)*72 + 32*ks + kg*8];
        #pragma unroll
        for (int n=0;n<4;n++)
          oacc[md][n] = __builtin_amdgcn_mfma_f32_16x16x32_bf16(vf, pf[n], oacc[md][n], 0,0,0);
      }
    }

    // store O
    short* yb = (short*)y;
    #pragma unroll
    for (int n=0;n<4;n++){
      int qt = 16*n + lr;
      if (qt >= 50) continue;
      #pragma unroll
      for (int md=0; md<2; md++){
        short4v pk;
        #pragma unroll
        for (int r=0;r<4;r++) pk[r] = bfs(oacc[md][n][r]);
        *(short4v*)&yb[(tok0+qt)*CDIM + h*32 + 16*md + 4*kg] = pk;
      }
    }
  }
}

// ---------------------------------------------------------------------------
extern "C" void kernel_launch(void* const* d_in, const int* in_sizes, int n_in,
                              void* d_out, int out_size, void* d_ws, size_t ws_size,
                              hipStream_t stream)
{
  const float* x_in   = (const float*)d_in[0];
  const float* maskp  = (const float*)d_in[1];
  const float* g0 = (const float*)d_in[2];  const float* b0 = (const float*)d_in[3];
  const float* g1 = (const float*)d_in[4];  const float* b1 = (const float*)d_in[5];
  const float* g2 = (const float*)d_in[6];  const float* b2 = (const float*)d_in[7];
  const float* ge = (const float*)d_in[8];  const float* be = (const float*)d_in[9];
  const float* w_qkv = (const float*)d_in[10];
  const float* w_proj= (const float*)d_in[11];
  const float* b_proj= (const float*)d_in[12];
  const float* rel_pos=(const float*)d_in[13];
  const float* w_fc1 = (const float*)d_in[14];
  const float* b_fc1 = (const float*)d_in[15];
  const float* w_fc2 = (const float*)d_in[16];
  const float* b_fc2 = (const float*)d_in[17];
  const float* w_exp = (const float*)d_in[18];
  const float* b_exp = (const float*)d_in[19];
  const float* w_lin = (const float*)d_in[20];
  const float* b_lin = (const float*)d_in[21];
  float* dout = (float*)d_out;

  const size_t NT = (size_t)NWIN * NTOK;

  size_t off = 0;
  auto alloc = [&](size_t bytes)->void* {
    void* p = (char*)d_ws + off;
    off += (bytes + 255) & ~(size_t)255;
    return p;
  };

  bf16* wqkv_b = (bf16*)alloc((size_t)QKVD*CDIM*2);
  bf16* wproj_b= (bf16*)alloc((size_t)CDIM*CDIM*2);
  bf16* wfc1_b = (bf16*)alloc((size_t)MLPH*CDIM*2);
  bf16* wlin_b = (bf16*)alloc((size_t)CDIM*DHID*2);
  bf16* wexpT_b= (bf16*)alloc((size_t)CDIM*DHID*2);
  bf16* wfc2T_b= (bf16*)alloc((size_t)MLPH*DHID*2);
  bf16* W_comb = (bf16*)alloc((size_t)CDIM*KTAIL*2);
  float* biasc = (float*)alloc((size_t)CDIM*4);
  float* xb    = (float*)alloc(NT*CDIM*4);
  bf16* clsln  = (bf16*)alloc((size_t)NWIN*CDIM*2);
  bf16* qkvcls = (bf16*)alloc((size_t)NWIN*QKVD*2);
  bf16* ycls   = (bf16*)alloc((size_t)NWIN*CDIM*2);

  // per-window: xln 38400 + ybfc 38400 + h1ext 345600 = 422400 (qkvc aliases h1ext)
  int CH_W = 2048;
  const size_t per_window = 422400ull;
  while (CH_W > 128 && off + (size_t)CH_W*per_window + 16384 > ws_size) CH_W >>= 1;
  const int CH_T = CH_W * NTOK;

  bf16*  xln   = (bf16*) alloc((size_t)CH_T*CDIM*2);
  bf16*  ybfc  = (bf16*) alloc((size_t)CH_T*CDIM*2);
  bf16*  h1ext = (bf16*) alloc((size_t)CH_T*KTAIL*2);
  bf16*  qkvc  = h1ext;   // alias: qkvc dead before h1ext is written

  // ---- precompute ----
  cvt4_kernel<<<512, 256, 0, stream>>>(
      w_qkv, wqkv_b, QKVD*CDIM,  w_proj, wproj_b, CDIM*CDIM,
      w_fc1, wfc1_b, MLPH*CDIM,  w_lin,  wlin_b,  CDIM*DHID);
  transpose_cvt_kernel<<<dim3(CDIM/32, DHID/32), 256, 0, stream>>>(w_exp, wexpT_b, DHID, CDIM);
  transpose_cvt_kernel<<<dim3(MLPH/32, DHID/32), 256, 0, stream>>>(w_fc2, wfc2T_b, DHID, MLPH);
  bias_combine_kernel<<<6, 64, 0, stream>>>(w_lin, b_lin, b_exp, b_fc2, biasc);
  gemm_wcmb_k<<<dim3(CDIM/128, CDIM/128), 256, 0, stream>>>(
      wlin_b, wexpT_b, W_comb, nullptr, nullptr, nullptr, CDIM, CDIM, DHID, DHID, KTAIL, 0);
  gemm_wcmb_k<<<dim3(MLPH/128, CDIM/128), 256, 0, stream>>>(
      wlin_b, wfc2T_b, W_comb + 384, nullptr, nullptr, nullptr, CDIM, MLPH, DHID, DHID, KTAIL, 0);

  // ---- cls path (writes only cls rows of xb) ----
  ln_kernel<false><<<NWIN/4, 256, 0, stream>>>(x_in, (long)NTOK*CDIM, g0, b0, clsln, NWIN);
  gemm_qkv_k<<<dim3(QKVD/128, NWIN/128), 256, 0, stream>>>(
      clsln, wqkv_b, qkvcls, nullptr, nullptr, nullptr, NWIN, QKVD, CDIM, CDIM, QKVD, 0);
  attn_cls_kernel<<<dim3(IMGS, NHEADS), 256, 0, stream>>>(qkvcls, ycls);
  gemm_projc_k<<<dim3(CDIM/128, NWIN/128), 256, 0, stream>>>(
      ycls, wproj_b, xb, b_proj, x_in, nullptr, NWIN, CDIM, CDIM, CDIM, NTOK*CDIM, NTOK*CDIM);

  // ---- main chunk loop ----
  const int nch = NWIN / CH_W;
  for (int c = 0; c < nch; c++){
    int w0 = c * CH_W;
    size_t t0 = (size_t)w0 * NTOK;
    float* xbc = xb + t0*CDIM;
    const float* xinc = x_in + t0*CDIM;
    float* doutc = dout + t0*CDIM;
    int MT = CH_T, MB = CH_T/128;

    ln_sel_kernel<<<MT/4, 256, 0, stream>>>(xbc, xinc, g1, b1, xln, MT);
    gemm_qkv_k<<<dim3(QKVD/128, MB), 256, 0, stream>>>(
        xln, wqkv_b, qkvc, nullptr, nullptr, nullptr, MT, QKVD, CDIM, CDIM, QKVD, 0);
    attn_win_mfma<<<dim3(CH_W), 128, 0, stream>>>(
        qkvc, maskp + (size_t)w0*2500, rel_pos, ybfc);
    gemm_projw_k<<<dim3(CDIM/128, MB), 256, 0, stream>>>(
        ybfc, wproj_b, xbc, b_proj, xbc, xinc, MT, CDIM, CDIM, CDIM, CDIM, CDIM);

    ln_dual_kernel<<<MT/4, 256, 0, stream>>>(xbc, ge, be, g2, b2, h1ext, KTAIL, ybfc, MT);

    gemm_fc1_k<<<dim3(MLPH/128, MB), 256, 0, stream>>>(
        ybfc, wfc1_b, h1ext + 384, b_fc1, nullptr, nullptr, MT, MLPH, CDIM, CDIM, KTAIL, 0);

    gemm_tail_k<<<dim3(CDIM/128, MB), 256, 0, stream>>>(
        h1ext, W_comb, doutc, biasc, nullptr, nullptr, MT, CDIM, KTAIL, KTAIL, CDIM, 0);
  }
}

// Round 18
// 1600.104 us; speedup vs baseline: 1.2202x; 1.0017x over previous
//
#include <hip/hip_runtime.h>
#include <hip/hip_bf16.h>
#include <math.h>

#define NHEADS 12
#define NTOK   50
#define NWIN   2048
#define IMGS   32
#define CDIM   384
#define QKVD   1152
#define DHID   768
#define MLPH   3072
#define KTAIL  3456   // 384 + 3072
#define SCALE_F 0.17677669529663687f

typedef short short8 __attribute__((ext_vector_type(8)));
typedef short short4v __attribute__((ext_vector_type(4)));
typedef short short2v __attribute__((ext_vector_type(2)));
typedef float f32x4  __attribute__((ext_vector_type(4)));
typedef __hip_bfloat16 bf16;

__device__ __forceinline__ float rcp_fast(float x){ return __builtin_amdgcn_rcpf(x); }

// tanh-form gelu (|err| ~1e-3) — LN paths (cold)
__device__ __forceinline__ float gelu_f(float x){
  float z = 0.7978845608028654f*(x + 0.044715f*x*x*x);
  float e = __expf(2.0f*z);
  return 0.5f*x*(1.0f + (1.0f - 2.0f*rcp_fast(e+1.0f)));
}
// sigmoid-form gelu — hot fc1 epilogue
__device__ __forceinline__ float gelu_fast(float x){
  float e = __expf(-1.702f*x);
  return x * rcp_fast(1.0f + e);
}
__device__ __forceinline__ short bfs(float x){
  bf16 h = __float2bfloat16(x); return *(short*)&h;
}

// ---------------- weights fp32 -> bf16 (4 tensors) ----------------
__global__ void cvt4_kernel(const float* s0, bf16* d0, int n0,
                            const float* s1, bf16* d1, int n1,
                            const float* s2, bf16* d2, int n2,
                            const float* s3, bf16* d3, int n3){
  int stride = gridDim.x*blockDim.x, g = blockIdx.x*blockDim.x + threadIdx.x;
  for (int i=g; i<n0; i+=stride) d0[i] = __float2bfloat16(s0[i]);
  for (int i=g; i<n1; i+=stride) d1[i] = __float2bfloat16(s1[i]);
  for (int i=g; i<n2; i+=stride) d2[i] = __float2bfloat16(s2[i]);
  for (int i=g; i<n3; i+=stride) d3[i] = __float2bfloat16(s3[i]);
}

// ---------------- transpose + cvt: src[R][Cc] fp32 -> dst[Cc][R] bf16 ------------
__global__ __launch_bounds__(256) void transpose_cvt_kernel(const float* __restrict__ src,
    bf16* __restrict__ dst, int R, int Cc){
  __shared__ float tile[32][33];
  int bx = blockIdx.x, by = blockIdx.y;
  int c = threadIdx.x & 31, r0 = threadIdx.x >> 5;
  #pragma unroll
  for (int rr = r0; rr < 32; rr += 8)
    tile[rr][c] = src[(size_t)(by*32+rr)*Cc + bx*32 + c];
  __syncthreads();
  #pragma unroll
  for (int rr = r0; rr < 32; rr += 8)
    dst[(size_t)(bx*32+rr)*R + by*32 + c] = __float2bfloat16(tile[c][rr]);
}

// ---------------- bias_c = b_lin + w_lin * (b_exp + b_fc2) ----------------
__global__ void bias_combine_kernel(const float* __restrict__ wlin,
    const float* __restrict__ b_lin, const float* __restrict__ b_exp,
    const float* __restrict__ b_fc2, float* __restrict__ biasc){
  int i = blockIdx.x*blockDim.x + threadIdx.x;
  if (i >= CDIM) return;
  float s = b_lin[i];
  for (int d=0; d<DHID; d++) s += wlin[(size_t)i*DHID+d]*(b_exp[d]+b_fc2[d]);
  biasc[i] = s;
}

// ---------------- LayerNorm, fp32 in -> bf16 out ----------------
template<bool GELU>
__global__ __launch_bounds__(256) void ln_kernel(const float* __restrict__ x, long ldx,
    const float* __restrict__ g, const float* __restrict__ b,
    bf16* __restrict__ y, int rows)
{
  int row = blockIdx.x*4 + (threadIdx.x>>6);
  if (row >= rows) return;
  int l = threadIdx.x & 63;
  const float2* xr = (const float2*)(x + (size_t)row*ldx);
  float2 v[3]; float s = 0.f;
  #pragma unroll
  for (int j=0;j<3;j++){ v[j] = xr[l + 64*j]; s += v[j].x + v[j].y; }
  #pragma unroll
  for (int off=32; off; off>>=1) s += __shfl_xor(s, off, 64);
  float mean = s * (1.0f/384.0f);
  float vs = 0.f;
  #pragma unroll
  for (int j=0;j<3;j++){ float dx=v[j].x-mean, dy=v[j].y-mean; vs += dx*dx+dy*dy; }
  #pragma unroll
  for (int off=32; off; off>>=1) vs += __shfl_xor(vs, off, 64);
  float rstd = rsqrtf(vs*(1.0f/384.0f) + 1e-5f);
  short2v* yr = (short2v*)(y + (size_t)row*384);
  const float2* gv = (const float2*)g; const float2* bv = (const float2*)b;
  #pragma unroll
  for (int j=0;j<3;j++){
    float2 gg = gv[l+64*j], bb = bv[l+64*j];
    float o0 = (v[j].x-mean)*rstd*gg.x + bb.x;
    float o1 = (v[j].y-mean)*rstd*gg.y + bb.y;
    if (GELU){ o0 = gelu_f(o0); o1 = gelu_f(o1); }
    short2v pk; pk[0]=bfs(o0); pk[1]=bfs(o1);
    yr[l+64*j] = pk;
  }
}

// ---- LayerNorm with row-conditional source: cls rows (row%50==0) from xa, else xbse
__global__ __launch_bounds__(256) void ln_sel_kernel(const float* __restrict__ xa,
    const float* __restrict__ xbse,
    const float* __restrict__ g, const float* __restrict__ b,
    bf16* __restrict__ y, int rows)
{
  int row = blockIdx.x*4 + (threadIdx.x>>6);
  if (row >= rows) return;
  int l = threadIdx.x & 63;
  const float* src = (row % 50 == 0) ? xa : xbse;
  const float2* xr = (const float2*)(src + (size_t)row*384);
  float2 v[3]; float s = 0.f;
  #pragma unroll
  for (int j=0;j<3;j++){ v[j] = xr[l + 64*j]; s += v[j].x + v[j].y; }
  #pragma unroll
  for (int off=32; off; off>>=1) s += __shfl_xor(s, off, 64);
  float mean = s * (1.0f/384.0f);
  float vs = 0.f;
  #pragma unroll
  for (int j=0;j<3;j++){ float dx=v[j].x-mean, dy=v[j].y-mean; vs += dx*dx+dy*dy; }
  #pragma unroll
  for (int off=32; off; off>>=1) vs += __shfl_xor(vs, off, 64);
  float rstd = rsqrtf(vs*(1.0f/384.0f) + 1e-5f);
  short2v* yr = (short2v*)(y + (size_t)row*384);
  const float2* gv = (const float2*)g; const float2* bv = (const float2*)b;
  #pragma unroll
  for (int j=0;j<3;j++){
    float2 gg = gv[l+64*j], bb = bv[l+64*j];
    short2v pk;
    pk[0]=bfs((v[j].x-mean)*rstd*gg.x + bb.x);
    pk[1]=bfs((v[j].y-mean)*rstd*gg.y + bb.y);
    yr[l+64*j] = pk;
  }
}

// ------- dual LayerNorm: one read, two outputs (expand-gelu @lde, mlp @384) -------
__global__ __launch_bounds__(256) void ln_dual_kernel(const float* __restrict__ x,
    const float* __restrict__ ge, const float* __restrict__ be,
    const float* __restrict__ g2, const float* __restrict__ b2,
    bf16* __restrict__ yeo, long lde, bf16* __restrict__ y2o, int rows)
{
  int row = blockIdx.x*4 + (threadIdx.x>>6);
  if (row >= rows) return;
  int l = threadIdx.x & 63;
  const float2* xr = (const float2*)(x + (size_t)row*384);
  float2 v[3]; float s = 0.f;
  #pragma unroll
  for (int j=0;j<3;j++){ v[j] = xr[l + 64*j]; s += v[j].x + v[j].y; }
  #pragma unroll
  for (int off=32; off; off>>=1) s += __shfl_xor(s, off, 64);
  float mean = s * (1.0f/384.0f);
  float vs = 0.f;
  #pragma unroll
  for (int j=0;j<3;j++){ float dx=v[j].x-mean, dy=v[j].y-mean; vs += dx*dx+dy*dy; }
  #pragma unroll
  for (int off=32; off; off>>=1) vs += __shfl_xor(vs, off, 64);
  float rstd = rsqrtf(vs*(1.0f/384.0f) + 1e-5f);
  short2v* ye = (short2v*)(yeo + (size_t)row*lde);
  short2v* y2 = (short2v*)(y2o + (size_t)row*384);
  const float2* gev = (const float2*)ge; const float2* bev = (const float2*)be;
  const float2* g2v = (const float2*)g2; const float2* b2v = (const float2*)b2;
  #pragma unroll
  for (int j=0;j<3;j++){
    float n0 = (v[j].x-mean)*rstd, n1 = (v[j].y-mean)*rstd;
    float2 gg = gev[l+64*j], bb = bev[l+64*j];
    short2v pe; pe[0]=bfs(gelu_f(n0*gg.x+bb.x)); pe[1]=bfs(gelu_f(n1*gg.y+bb.y));
    ye[l+64*j] = pe;
    gg = g2v[l+64*j]; bb = b2v[l+64*j];
    short2v p2; p2[0]=bfs(n0*gg.x+bb.x); p2[1]=bfs(n1*gg.y+bb.y);
    y2[l+64*j] = p2;
  }
}

// ---------------- GEMM: C[M,N] = A[M,K](bf16, lda) * B[N,K]^T (ldb), fp32 acc -----
// 128x128 tile, 4 waves, depth-2 prefetch (3 LDS buffers, counted vmcnt(4)),
// XCD-bijective swizzle. [proven]  GELU: 0=none 1=sigmoid-fast
// RES: 0=none 1=fp32  3=row-conditional fp32 (cls row%50==0 -> res, else res2)
template<bool OUT_BF16, bool BIAS, int RES, int GELU>
__device__ __forceinline__ void gemm_dev(
    const bf16* __restrict__ A, const bf16* __restrict__ B, void* Cv,
    const float* __restrict__ bias, const void* res, const void* res2,
    int M, int N, int K, int lda, int ldb, int ldc, int ldres)
{
  __shared__ short As[3][128*32];
  __shared__ short Bs[3][128*32];
  const int t  = threadIdx.x;
  const int l  = t & 63;
  const int w  = t >> 6;
  const int wr = w >> 1, wc = w & 1;
  const int lr = l & 15, kg = l >> 4;

  const int nwg = gridDim.x * gridDim.y;
  const int lin = blockIdx.y * gridDim.x + blockIdx.x;
  const int q8 = nwg >> 3, r8 = nwg & 7;
  const int xcd = lin & 7, slot = lin >> 3;
  const int swz = (xcd < r8) ? (xcd*(q8+1) + slot) : (r8*(q8+1) + (xcd-r8)*q8 + slot);
  const int by = swz / gridDim.x, bx = swz - by*gridDim.x;

  const int bm = by * 128, bn = bx * 128;
  const short* Ag = (const short*)A;
  const short* Bg = (const short*)B;

  const int eo0 = w*1024 + l*8;
  const int rowS0 = eo0 >> 5, colS0 = eo0 & 31;
  const int eo1 = eo0 + 512;
  const int rowS1 = eo1 >> 5, colS1 = eo1 & 31;

  #define STAGE(k0, b) do { \
    __builtin_amdgcn_global_load_lds( \
      (const __attribute__((address_space(1))) void*)&Ag[(size_t)(bm+rowS0)*lda + (k0) + colS0], \
      (__attribute__((address_space(3))) void*)((char*)&As[b][0] + w*2048), 16, 0, 0); \
    __builtin_amdgcn_global_load_lds( \
      (const __attribute__((address_space(1))) void*)&Bg[(size_t)(bn+rowS0)*ldb + (k0) + colS0], \
      (__attribute__((address_space(3))) void*)((char*)&Bs[b][0] + w*2048), 16, 0, 0); \
    __builtin_amdgcn_global_load_lds( \
      (const __attribute__((address_space(1))) void*)&Ag[(size_t)(bm+rowS1)*lda + (k0) + colS1], \
      (__attribute__((address_space(3))) void*)((char*)&As[b][0] + w*2048 + 1024), 16, 0, 0); \
    __builtin_amdgcn_global_load_lds( \
      (const __attribute__((address_space(1))) void*)&Bg[(size_t)(bn+rowS1)*ldb + (k0) + colS1], \
      (__attribute__((address_space(3))) void*)((char*)&Bs[b][0] + w*2048 + 1024), 16, 0, 0); \
  } while(0)

  f32x4 acc[4][4] = {};

  STAGE(0, 0);
  STAGE(32, 1);
  asm volatile("s_waitcnt vmcnt(4)" ::: "memory");
  __builtin_amdgcn_s_barrier();

  int cur = 0, nb = 2;
  for (int k0 = 0; k0 < K; k0 += 32) {
    const bool more = (k0 + 64 < K);
    if (more) STAGE(k0 + 64, nb);

    short8 af[4], bfm[4];
    #pragma unroll
    for (int m=0;m<4;m++) af[m]  = *(const short8*)(&As[cur][(wr*64 + m*16 + lr)*32 + kg*8]);
    #pragma unroll
    for (int n=0;n<4;n++) bfm[n] = *(const short8*)(&Bs[cur][(wc*64 + n*16 + lr)*32 + kg*8]);
    __builtin_amdgcn_s_setprio(1);
    #pragma unroll
    for (int m=0;m<4;m++)
      #pragma unroll
      for (int n=0;n<4;n++)
        acc[m][n] = __builtin_amdgcn_mfma_f32_16x16x32_bf16(af[m], bfm[n], acc[m][n], 0,0,0);
    __builtin_amdgcn_s_setprio(0);

    if (more) { asm volatile("s_waitcnt vmcnt(4)" ::: "memory"); }
    else      { asm volatile("s_waitcnt vmcnt(0)" ::: "memory"); }
    __builtin_amdgcn_s_barrier();
    cur = (cur==2) ? 0 : cur+1;
    nb  = (nb==2)  ? 0 : nb+1;
  }
  #undef STAGE

  #pragma unroll
  for (int m=0;m<4;m++){
    int row0 = bm + wr*64 + m*16 + kg*4;
    #pragma unroll
    for (int n=0;n<4;n++){
      int col = bn + wc*64 + n*16 + lr;
      float bv = BIAS ? bias[col] : 0.0f;
      #pragma unroll
      for (int r=0;r<4;r++){
        float val = acc[m][n][r] + bv;
        if (RES == 1) val += ((const float*)res)[(size_t)(row0+r)*ldres + col];
        if (RES == 3){
          int grow = row0 + r;
          const float* rs = ((grow % 50) == 0) ? (const float*)res : (const float*)res2;
          val += rs[(size_t)grow*ldres + col];
        }
        if (GELU == 1) val = gelu_fast(val);
        if (OUT_BF16) ((bf16*)Cv)[(size_t)(row0+r)*ldc + col] = __float2bfloat16(val);
        else          ((float*)Cv)[(size_t)(row0+r)*ldc + col] = val;
      }
    }
  }
}

#define GEMM_K(NAME, OB, BI, RE, GE) \
__global__ __launch_bounds__(256) void NAME( \
    const bf16* __restrict__ A, const bf16* __restrict__ B, void* Cv, \
    const float* __restrict__ bias, const void* res, const void* res2, \
    int M, int N, int K, int lda, int ldc, int ldres){ \
  gemm_dev<OB,BI,RE,GE>(A,B,Cv,bias,res,res2,M,N,K,lda,K,ldc,ldres); }

GEMM_K(gemm_qkv_k,   true,  false, 0, 0)   // qkv: bf16 out
GEMM_K(gemm_projc_k, false, true,  1, 0)   // cls proj: +bias, +fp32 res, fp32 out
GEMM_K(gemm_projw_k, false, true,  3, 0)   // window proj: row-conditional residual
GEMM_K(gemm_fc1_k,   true,  true,  0, 1)   // fc1: +bias, fast-gelu, bf16 out (ldc=KTAIL)
GEMM_K(gemm_wcmb_k,  true,  false, 0, 0)   // weight-combo precompute, bf16 out

// tail keeps explicit ldb=KTAIL plumbing (A lda=KTAIL, B=W_comb ldb=KTAIL)
__global__ __launch_bounds__(256) void gemm_tail_k(
    const bf16* __restrict__ A, const bf16* __restrict__ B, void* Cv,
    const float* __restrict__ bias, const void* res, const void* res2,
    int M, int N, int K, int lda, int ldc, int ldres){
  gemm_dev<false,true,0,0>(A,B,Cv,bias,res,res2,M,N,K,lda,KTAIL,ldc,ldres);
}

// ---------------- cls attention (small; unchanged) ----------------
__global__ __launch_bounds__(256) void attn_cls_kernel(const bf16* __restrict__ qkv,
                                                       bf16* __restrict__ y)
{
  int img = blockIdx.x, h = blockIdx.y;
  __shared__ float q[64][33], k[64][33], v[64][33];
  __shared__ float s[64][65];
  int t = threadIdx.x;
  for (int idx=t; idx<64*32; idx+=256){
    int i = idx>>5, d = idx&31;
    const bf16* base = qkv + ((size_t)(img*64+i))*QKVD + h*32 + d;
    q[i][d] = __bfloat162float(base[0]);
    k[i][d] = __bfloat162float(base[384]);
    v[i][d] = __bfloat162float(base[768]);
  }
  __syncthreads();
  for (int idx=t; idx<64*64; idx+=256){
    int i = idx>>6, j = idx&63;
    float a = 0.f;
    #pragma unroll
    for (int d=0; d<32; d++) a += q[i][d]*k[j][d];
    s[i][j] = a * SCALE_F;
  }
  __syncthreads();
  if (t < 64){
    float m = -1e30f;
    for (int j=0;j<64;j++) m = fmaxf(m, s[t][j]);
    float sum = 0.f;
    for (int j=0;j<64;j++){ float e = __expf(s[t][j]-m); s[t][j]=e; sum+=e; }
    float inv = rcp_fast(sum);
    for (int j=0;j<64;j++) s[t][j] *= inv;
  }
  __syncthreads();
  for (int idx=t; idx<64*32; idx+=256){
    int i = idx>>5, d = idx&31;
    float a = 0.f;
    for (int j=0;j<64;j++) a += s[i][j]*v[j][d];
    y[((size_t)(img*64+i))*CDIM + h*32 + d] = __float2bfloat16(a);
  }
}

// ======== MFMA window attention, head-batched (proven round-17) ========
__global__ __launch_bounds__(128) void attn_win_mfma(const bf16* __restrict__ qkv,
    const float* __restrict__ mask, const float* __restrict__ rel_pos,
    bf16* __restrict__ y)
{
  const int lw = blockIdx.x;
  const int tid = threadIdx.x;
  const int w = tid >> 6;
  const int l = tid & 63;
  const int lr = l & 15, kg = l >> 4;

  __shared__ float msk[2500];
  __shared__ float rp_w[2][169];
  __shared__ short PldsA[2][64*72];
  __shared__ short VTlA[2][32*72];

  const size_t tok0 = (size_t)lw * NTOK;
  const short* qbase = (const short*)qkv;

  for (int i = tid; i < 2500; i += 128) msk[i] = mask[(size_t)lw*2500 + i];
  __syncthreads();

  short* Plds = &PldsA[w][0];
  short* VTl  = &VTlA[w][0];
  float* rp   = &rp_w[w][0];

  for (int hh = 0; hh < 6; hh++){
    const int h = w*6 + hh;

    for (int i = l; i < 169; i += 64) rp[i] = rel_pos[i*NHEADS + h];

    short8 qf[4], kf[4];
    #pragma unroll
    for (int n=0;n<4;n++){
      int qt = 16*n + lr;
      if (qt < 50) qf[n] = *(const short8*)&qbase[(tok0+qt)*QKVD + h*32 + kg*8];
      else         qf[n] = short8(0);
    }
    #pragma unroll
    for (int m=0;m<4;m++){
      int kt = 16*m + lr;
      if (kt < 50) kf[m] = *(const short8*)&qbase[(tok0+kt)*QKVD + 384 + h*32 + kg*8];
      else         kf[m] = short8(0);
    }

    {
      short vv[32];
      if (l < 50){
        const short8* vp = (const short8*)&qbase[(tok0+l)*QKVD + 768 + h*32];
        #pragma unroll
        for (int jj=0;jj<4;jj++){ short8 xv = vp[jj];
          #pragma unroll
          for (int e=0;e<8;e++) vv[jj*8+e] = xv[e]; }
      } else {
        #pragma unroll
        for (int d=0; d<32; d++) vv[d]=0;
      }
      #pragma unroll
      for (int d=0; d<32; d++) VTl[d*72 + l] = vv[d];
    }

    f32x4 sacc[4][4] = {};
    #pragma unroll
    for (int m=0;m<4;m++)
      #pragma unroll
      for (int n=0;n<4;n++)
        sacc[m][n] = __builtin_amdgcn_mfma_f32_16x16x32_bf16(kf[m], qf[n], sacc[m][n], 0,0,0);

    float sv[4][4][4];
    #pragma unroll
    for (int m=0;m<4;m++){
      #pragma unroll
      for (int r=0;r<4;r++){
        int kt = 16*m + 4*kg + r;
        #pragma unroll
        for (int n=0;n<4;n++){
          int qt = 16*n + lr;
          float a;
          if (kt < 50 && qt < 50){
            a = sacc[m][n][r] * SCALE_F;
            if (kt>=1 && qt>=1){
              int qi=qt-1, kj=kt-1;
              int ridx = ((qi/7)-(kj/7)+6)*13 + (qi%7)-(kj%7)+6;
              a += rp[ridx];
            }
            a += msk[qt*50+kt];
          } else a = -1e30f;
          sv[m][r][n] = a;
        }
      }
    }

    #pragma unroll
    for (int n=0;n<4;n++){
      float mx = -1e30f;
      #pragma unroll
      for (int m=0;m<4;m++)
        #pragma unroll
        for (int r=0;r<4;r++) mx = fmaxf(mx, sv[m][r][n]);
      mx = fmaxf(mx, __shfl_xor(mx, 16));
      mx = fmaxf(mx, __shfl_xor(mx, 32));
      float sum = 0.f;
      float pv[4][4];
      #pragma unroll
      for (int m=0;m<4;m++)
        #pragma unroll
        for (int r=0;r<4;r++){ float p = __expf(sv[m][r][n]-mx); pv[m][r]=p; sum+=p; }
      sum += __shfl_xor(sum, 16);
      sum += __shfl_xor(sum, 32);
      float inv = rcp_fast(sum);
      int qrow = (16*n + lr)*72;
      #pragma unroll
      for (int m=0;m<4;m++){
        short4v pk;
        #pragma unroll
        for (int r=0;r<4;r++) pk[r] = bfs(pv[m][r]*inv);
        *(short4v*)&Plds[qrow + 16*m + 4*kg] = pk;
      }
    }

    f32x4 oacc[2][4] = {};
    #pragma unroll
    for (int ks=0; ks<2; ks++){
      short8 pf[4];
      #pragma unroll
      for (int n=0;n<4;n++)
        pf[n] = *(const short8*)&Plds[(16*n+lr)*72 + 32*ks + kg*8];
      #pragma unroll
      for (int md=0; md<2; md++){
        short8 vf = *(const short8*)&VTl[(16*md+lr)*72 + 32*ks + kg*8];
        #pragma unroll
        for (int n=0;n<4;n++)
          oacc[md][n] = __builtin_amdgcn_mfma_f32_16x16x32_bf16(vf, pf[n], oacc[md][n], 0,0,0);
      }
    }

    short* yb = (short*)y;
    #pragma unroll
    for (int n=0;n<4;n++){
      int qt = 16*n + lr;
      if (qt >= 50) continue;
      #pragma unroll
      for (int md=0; md<2; md++){
        short4v pk;
        #pragma unroll
        for (int r=0;r<4;r++) pk[r] = bfs(oacc[md][n][r]);
        *(short4v*)&yb[(tok0+qt)*CDIM + h*32 + 16*md + 4*kg] = pk;
      }
    }
  }
}

// ---------------------------------------------------------------------------
extern "C" void kernel_launch(void* const* d_in, const int* in_sizes, int n_in,
                              void* d_out, int out_size, void* d_ws, size_t ws_size,
                              hipStream_t stream)
{
  const float* x_in   = (const float*)d_in[0];
  const float* maskp  = (const float*)d_in[1];
  const float* g0 = (const float*)d_in[2];  const float* b0 = (const float*)d_in[3];
  const float* g1 = (const float*)d_in[4];  const float* b1 = (const float*)d_in[5];
  const float* g2 = (const float*)d_in[6];  const float* b2 = (const float*)d_in[7];
  const float* ge = (const float*)d_in[8];  const float* be = (const float*)d_in[9];
  const float* w_qkv = (const float*)d_in[10];
  const float* w_proj= (const float*)d_in[11];
  const float* b_proj= (const float*)d_in[12];
  const float* rel_pos=(const float*)d_in[13];
  const float* w_fc1 = (const float*)d_in[14];
  const float* b_fc1 = (const float*)d_in[15];
  const float* w_fc2 = (const float*)d_in[16];
  const float* b_fc2 = (const float*)d_in[17];
  const float* w_exp = (const float*)d_in[18];
  const float* b_exp = (const float*)d_in[19];
  const float* w_lin = (const float*)d_in[20];
  const float* b_lin = (const float*)d_in[21];
  float* dout = (float*)d_out;

  const size_t NT = (size_t)NWIN * NTOK;

  size_t off = 0;
  auto alloc = [&](size_t bytes)->void* {
    void* p = (char*)d_ws + off;
    off += (bytes + 255) & ~(size_t)255;
    return p;
  };

  bf16* wqkv_b = (bf16*)alloc((size_t)QKVD*CDIM*2);
  bf16* wproj_b= (bf16*)alloc((size_t)CDIM*CDIM*2);
  bf16* wfc1_b = (bf16*)alloc((size_t)MLPH*CDIM*2);
  bf16* wlin_b = (bf16*)alloc((size_t)CDIM*DHID*2);
  bf16* wexpT_b= (bf16*)alloc((size_t)CDIM*DHID*2);
  bf16* wfc2T_b= (bf16*)alloc((size_t)MLPH*DHID*2);
  bf16* W_comb = (bf16*)alloc((size_t)CDIM*KTAIL*2);
  float* biasc = (float*)alloc((size_t)CDIM*4);
  float* xb    = (float*)alloc(NT*CDIM*4);
  bf16* clsln  = (bf16*)alloc((size_t)NWIN*CDIM*2);
  bf16* qkvcls = (bf16*)alloc((size_t)NWIN*QKVD*2);
  bf16* ycls   = (bf16*)alloc((size_t)NWIN*CDIM*2);

  // per-window: xln 38400 + ybfc 38400 + h1ext 345600 = 422400 (qkvc aliases h1ext)
  int CH_W = 2048;
  const size_t per_window = 422400ull;
  while (CH_W > 128 && off + (size_t)CH_W*per_window + 16384 > ws_size) CH_W >>= 1;
  const int CH_T = CH_W * NTOK;

  bf16*  xln   = (bf16*) alloc((size_t)CH_T*CDIM*2);
  bf16*  ybfc  = (bf16*) alloc((size_t)CH_T*CDIM*2);
  bf16*  h1ext = (bf16*) alloc((size_t)CH_T*KTAIL*2);
  bf16*  qkvc  = h1ext;   // alias: qkvc dead before h1ext is written

  // ---- precompute ----
  cvt4_kernel<<<512, 256, 0, stream>>>(
      w_qkv, wqkv_b, QKVD*CDIM,  w_proj, wproj_b, CDIM*CDIM,
      w_fc1, wfc1_b, MLPH*CDIM,  w_lin,  wlin_b,  CDIM*DHID);
  transpose_cvt_kernel<<<dim3(CDIM/32, DHID/32), 256, 0, stream>>>(w_exp, wexpT_b, DHID, CDIM);
  transpose_cvt_kernel<<<dim3(MLPH/32, DHID/32), 256, 0, stream>>>(w_fc2, wfc2T_b, DHID, MLPH);
  bias_combine_kernel<<<6, 64, 0, stream>>>(w_lin, b_lin, b_exp, b_fc2, biasc);
  gemm_wcmb_k<<<dim3(CDIM/128, CDIM/128), 256, 0, stream>>>(
      wlin_b, wexpT_b, W_comb, nullptr, nullptr, nullptr, CDIM, CDIM, DHID, DHID, KTAIL, 0);
  gemm_wcmb_k<<<dim3(MLPH/128, CDIM/128), 256, 0, stream>>>(
      wlin_b, wfc2T_b, W_comb + 384, nullptr, nullptr, nullptr, CDIM, MLPH, DHID, DHID, KTAIL, 0);

  // ---- cls path (writes only cls rows of xb) ----
  ln_kernel<false><<<NWIN/4, 256, 0, stream>>>(x_in, (long)NTOK*CDIM, g0, b0, clsln, NWIN);
  gemm_qkv_k<<<dim3(QKVD/128, NWIN/128), 256, 0, stream>>>(
      clsln, wqkv_b, qkvcls, nullptr, nullptr, nullptr, NWIN, QKVD, CDIM, CDIM, QKVD, 0);
  attn_cls_kernel<<<dim3(IMGS, NHEADS), 256, 0, stream>>>(qkvcls, ycls);
  gemm_projc_k<<<dim3(CDIM/128, NWIN/128), 256, 0, stream>>>(
      ycls, wproj_b, xb, b_proj, x_in, nullptr, NWIN, CDIM, CDIM, CDIM, NTOK*CDIM, NTOK*CDIM);

  // ---- main chunk loop ----
  const int nch = NWIN / CH_W;
  for (int c = 0; c < nch; c++){
    int w0 = c * CH_W;
    size_t t0 = (size_t)w0 * NTOK;
    float* xbc = xb + t0*CDIM;
    const float* xinc = x_in + t0*CDIM;
    float* doutc = dout + t0*CDIM;
    int MT = CH_T, MB = CH_T/128;

    ln_sel_kernel<<<MT/4, 256, 0, stream>>>(xbc, xinc, g1, b1, xln, MT);
    gemm_qkv_k<<<dim3(QKVD/128, MB), 256, 0, stream>>>(
        xln, wqkv_b, qkvc, nullptr, nullptr, nullptr, MT, QKVD, CDIM, CDIM, QKVD, 0);
    attn_win_mfma<<<dim3(CH_W), 128, 0, stream>>>(
        qkvc, maskp + (size_t)w0*2500, rel_pos, ybfc);
    gemm_projw_k<<<dim3(CDIM/128, MB), 256, 0, stream>>>(
        ybfc, wproj_b, xbc, b_proj, xbc, xinc, MT, CDIM, CDIM, CDIM, CDIM, CDIM);

    // ---- MLP pipeline sub-chunked so each h1ext slice stays L3-resident ----
    // sub = 512 windows -> h1ext slice 177 MB < 256 MB L3; tail reads L3-hot data.
    const int NSUB = (CH_W >= 1024) ? 2 : 1;
    const int MS = MT / NSUB, MSB = MS / 128;
    for (int s = 0; s < NSUB; s++){
      size_t r0 = (size_t)s * MS;
      float* xbs = xbc + r0*CDIM;
      bf16*  h1s = h1ext + r0*KTAIL;
      bf16*  ybs = ybfc + r0*CDIM;
      float* dos = doutc + r0*CDIM;

      ln_dual_kernel<<<MS/4, 256, 0, stream>>>(xbs, ge, be, g2, b2, h1s, KTAIL, ybs, MS);

      gemm_fc1_k<<<dim3(MLPH/128, MSB), 256, 0, stream>>>(
          ybs, wfc1_b, h1s + 384, b_fc1, nullptr, nullptr, MS, MLPH, CDIM, CDIM, KTAIL, 0);

      gemm_tail_k<<<dim3(CDIM/128, MSB), 256, 0, stream>>>(
          h1s, W_comb, dos, biasc, nullptr, nullptr, MS, CDIM, KTAIL, KTAIL, CDIM, 0);
    }
  }
}

// Round 19
// 1484.379 us; speedup vs baseline: 1.3153x; 1.0780x over previous
//
#include <hip/hip_runtime.h>
#include <hip/hip_bf16.h>
#include <math.h>

#define NHEADS 12
#define NTOK   50
#define NWIN   2048
#define IMGS   32
#define CDIM   384
#define QKVD   1152
#define DHID   768
#define MLPH   3072
#define KTAIL  3456   // 384 + 3072
#define SCALE_F 0.17677669529663687f

typedef short short8 __attribute__((ext_vector_type(8)));
typedef short short4v __attribute__((ext_vector_type(4)));
typedef short short2v __attribute__((ext_vector_type(2)));
typedef float f32x4  __attribute__((ext_vector_type(4)));
typedef __hip_bfloat16 bf16;

__device__ __forceinline__ float rcp_fast(float x){ return __builtin_amdgcn_rcpf(x); }

// tanh-form gelu (|err| ~1e-3) — LN paths (cold)
__device__ __forceinline__ float gelu_f(float x){
  float z = 0.7978845608028654f*(x + 0.044715f*x*x*x);
  float e = __expf(2.0f*z);
  return 0.5f*x*(1.0f + (1.0f - 2.0f*rcp_fast(e+1.0f)));
}
// sigmoid-form gelu — hot fc1 epilogue
__device__ __forceinline__ float gelu_fast(float x){
  float e = __expf(-1.702f*x);
  return x * rcp_fast(1.0f + e);
}
__device__ __forceinline__ short bfs(float x){
  bf16 h = __float2bfloat16(x); return *(short*)&h;
}

// ---------------- weights fp32 -> bf16 (4 tensors) ----------------
__global__ void cvt4_kernel(const float* s0, bf16* d0, int n0,
                            const float* s1, bf16* d1, int n1,
                            const float* s2, bf16* d2, int n2,
                            const float* s3, bf16* d3, int n3){
  int stride = gridDim.x*blockDim.x, g = blockIdx.x*blockDim.x + threadIdx.x;
  for (int i=g; i<n0; i+=stride) d0[i] = __float2bfloat16(s0[i]);
  for (int i=g; i<n1; i+=stride) d1[i] = __float2bfloat16(s1[i]);
  for (int i=g; i<n2; i+=stride) d2[i] = __float2bfloat16(s2[i]);
  for (int i=g; i<n3; i+=stride) d3[i] = __float2bfloat16(s3[i]);
}

// ---------------- transpose + cvt: src[R][Cc] fp32 -> dst[Cc][R] bf16 ------------
__global__ __launch_bounds__(256) void transpose_cvt_kernel(const float* __restrict__ src,
    bf16* __restrict__ dst, int R, int Cc){
  __shared__ float tile[32][33];
  int bx = blockIdx.x, by = blockIdx.y;
  int c = threadIdx.x & 31, r0 = threadIdx.x >> 5;
  #pragma unroll
  for (int rr = r0; rr < 32; rr += 8)
    tile[rr][c] = src[(size_t)(by*32+rr)*Cc + bx*32 + c];
  __syncthreads();
  #pragma unroll
  for (int rr = r0; rr < 32; rr += 8)
    dst[(size_t)(bx*32+rr)*R + by*32 + c] = __float2bfloat16(tile[c][rr]);
}

// ---------------- bias_c = b_lin + w_lin * (b_exp + b_fc2) ----------------
__global__ void bias_combine_kernel(const float* __restrict__ wlin,
    const float* __restrict__ b_lin, const float* __restrict__ b_exp,
    const float* __restrict__ b_fc2, float* __restrict__ biasc){
  int i = blockIdx.x*blockDim.x + threadIdx.x;
  if (i >= CDIM) return;
  float s = b_lin[i];
  for (int d=0; d<DHID; d++) s += wlin[(size_t)i*DHID+d]*(b_exp[d]+b_fc2[d]);
  biasc[i] = s;
}

// ---------------- LayerNorm, fp32 in -> bf16 out ----------------
template<bool GELU>
__global__ __launch_bounds__(256) void ln_kernel(const float* __restrict__ x, long ldx,
    const float* __restrict__ g, const float* __restrict__ b,
    bf16* __restrict__ y, int rows)
{
  int row = blockIdx.x*4 + (threadIdx.x>>6);
  if (row >= rows) return;
  int l = threadIdx.x & 63;
  const float2* xr = (const float2*)(x + (size_t)row*ldx);
  float2 v[3]; float s = 0.f;
  #pragma unroll
  for (int j=0;j<3;j++){ v[j] = xr[l + 64*j]; s += v[j].x + v[j].y; }
  #pragma unroll
  for (int off=32; off; off>>=1) s += __shfl_xor(s, off, 64);
  float mean = s * (1.0f/384.0f);
  float vs = 0.f;
  #pragma unroll
  for (int j=0;j<3;j++){ float dx=v[j].x-mean, dy=v[j].y-mean; vs += dx*dx+dy*dy; }
  #pragma unroll
  for (int off=32; off; off>>=1) vs += __shfl_xor(vs, off, 64);
  float rstd = rsqrtf(vs*(1.0f/384.0f) + 1e-5f);
  short2v* yr = (short2v*)(y + (size_t)row*384);
  const float2* gv = (const float2*)g; const float2* bv = (const float2*)b;
  #pragma unroll
  for (int j=0;j<3;j++){
    float2 gg = gv[l+64*j], bb = bv[l+64*j];
    float o0 = (v[j].x-mean)*rstd*gg.x + bb.x;
    float o1 = (v[j].y-mean)*rstd*gg.y + bb.y;
    if (GELU){ o0 = gelu_f(o0); o1 = gelu_f(o1); }
    short2v pk; pk[0]=bfs(o0); pk[1]=bfs(o1);
    yr[l+64*j] = pk;
  }
}

// ---- LayerNorm with row-conditional source: cls rows (row%50==0) from xa, else xbse
__global__ __launch_bounds__(256) void ln_sel_kernel(const float* __restrict__ xa,
    const float* __restrict__ xbse,
    const float* __restrict__ g, const float* __restrict__ b,
    bf16* __restrict__ y, int rows)
{
  int row = blockIdx.x*4 + (threadIdx.x>>6);
  if (row >= rows) return;
  int l = threadIdx.x & 63;
  const float* src = (row % 50 == 0) ? xa : xbse;
  const float2* xr = (const float2*)(src + (size_t)row*384);
  float2 v[3]; float s = 0.f;
  #pragma unroll
  for (int j=0;j<3;j++){ v[j] = xr[l + 64*j]; s += v[j].x + v[j].y; }
  #pragma unroll
  for (int off=32; off; off>>=1) s += __shfl_xor(s, off, 64);
  float mean = s * (1.0f/384.0f);
  float vs = 0.f;
  #pragma unroll
  for (int j=0;j<3;j++){ float dx=v[j].x-mean, dy=v[j].y-mean; vs += dx*dx+dy*dy; }
  #pragma unroll
  for (int off=32; off; off>>=1) vs += __shfl_xor(vs, off, 64);
  float rstd = rsqrtf(vs*(1.0f/384.0f) + 1e-5f);
  short2v* yr = (short2v*)(y + (size_t)row*384);
  const float2* gv = (const float2*)g; const float2* bv = (const float2*)b;
  #pragma unroll
  for (int j=0;j<3;j++){
    float2 gg = gv[l+64*j], bb = bv[l+64*j];
    short2v pk;
    pk[0]=bfs((v[j].x-mean)*rstd*gg.x + bb.x);
    pk[1]=bfs((v[j].y-mean)*rstd*gg.y + bb.y);
    yr[l+64*j] = pk;
  }
}

// ------- dual LayerNorm: one read, two outputs (expand-gelu @lde, mlp @384) -------
__global__ __launch_bounds__(256) void ln_dual_kernel(const float* __restrict__ x,
    const float* __restrict__ ge, const float* __restrict__ be,
    const float* __restrict__ g2, const float* __restrict__ b2,
    bf16* __restrict__ yeo, long lde, bf16* __restrict__ y2o, int rows)
{
  int row = blockIdx.x*4 + (threadIdx.x>>6);
  if (row >= rows) return;
  int l = threadIdx.x & 63;
  const float2* xr = (const float2*)(x + (size_t)row*384);
  float2 v[3]; float s = 0.f;
  #pragma unroll
  for (int j=0;j<3;j++){ v[j] = xr[l + 64*j]; s += v[j].x + v[j].y; }
  #pragma unroll
  for (int off=32; off; off>>=1) s += __shfl_xor(s, off, 64);
  float mean = s * (1.0f/384.0f);
  float vs = 0.f;
  #pragma unroll
  for (int j=0;j<3;j++){ float dx=v[j].x-mean, dy=v[j].y-mean; vs += dx*dx+dy*dy; }
  #pragma unroll
  for (int off=32; off; off>>=1) vs += __shfl_xor(vs, off, 64);
  float rstd = rsqrtf(vs*(1.0f/384.0f) + 1e-5f);
  short2v* ye = (short2v*)(yeo + (size_t)row*lde);
  short2v* y2 = (short2v*)(y2o + (size_t)row*384);
  const float2* gev = (const float2*)ge; const float2* bev = (const float2*)be;
  const float2* g2v = (const float2*)g2; const float2* b2v = (const float2*)b2;
  #pragma unroll
  for (int j=0;j<3;j++){
    float n0 = (v[j].x-mean)*rstd, n1 = (v[j].y-mean)*rstd;
    float2 gg = gev[l+64*j], bb = bev[l+64*j];
    short2v pe; pe[0]=bfs(gelu_f(n0*gg.x+bb.x)); pe[1]=bfs(gelu_f(n1*gg.y+bb.y));
    ye[l+64*j] = pe;
    gg = g2v[l+64*j]; bb = b2v[l+64*j];
    short2v p2; p2[0]=bfs(n0*gg.x+bb.x); p2[1]=bfs(n1*gg.y+bb.y);
    y2[l+64*j] = p2;
  }
}

// ---------------- GEMM: C[M,N] = A[M,K](bf16, lda) * B[N,K]^T (ldb), fp32 acc -----
// 128x128 tile, 4 waves, depth-2 prefetch (3 LDS buffers, counted vmcnt(4)),
// XCD-bijective swizzle. [proven]  GELU: 0=none 1=sigmoid-fast
// RES: 0=none 1=fp32  3=row-conditional fp32 (cls row%50==0 -> res, else res2)
// bf16 output: epilogue bounces tile through LDS -> 16B coalesced stores
// (per-element bf16 stores were 32B segments = 2x HBM write amplification).
template<bool OUT_BF16, bool BIAS, int RES, int GELU>
__device__ __forceinline__ void gemm_dev(
    const bf16* __restrict__ A, const bf16* __restrict__ B, void* Cv,
    const float* __restrict__ bias, const void* res, const void* res2,
    int M, int N, int K, int lda, int ldb, int ldc, int ldres)
{
  __shared__ short SH[24576];   // staging: As=SH[0..12287], Bs=SH[12288..24575]
  short (*As)[4096] = (short(*)[4096])SH;
  short (*Bs)[4096] = (short(*)[4096])(SH + 12288);
  const int t  = threadIdx.x;
  const int l  = t & 63;
  const int w  = t >> 6;
  const int wr = w >> 1, wc = w & 1;
  const int lr = l & 15, kg = l >> 4;

  const int nwg = gridDim.x * gridDim.y;
  const int lin = blockIdx.y * gridDim.x + blockIdx.x;
  const int q8 = nwg >> 3, r8 = nwg & 7;
  const int xcd = lin & 7, slot = lin >> 3;
  const int swz = (xcd < r8) ? (xcd*(q8+1) + slot) : (r8*(q8+1) + (xcd-r8)*q8 + slot);
  const int by = swz / gridDim.x, bx = swz - by*gridDim.x;

  const int bm = by * 128, bn = bx * 128;
  const short* Ag = (const short*)A;
  const short* Bg = (const short*)B;

  const int eo0 = w*1024 + l*8;
  const int rowS0 = eo0 >> 5, colS0 = eo0 & 31;
  const int eo1 = eo0 + 512;
  const int rowS1 = eo1 >> 5, colS1 = eo1 & 31;

  #define STAGE(k0, b) do { \
    __builtin_amdgcn_global_load_lds( \
      (const __attribute__((address_space(1))) void*)&Ag[(size_t)(bm+rowS0)*lda + (k0) + colS0], \
      (__attribute__((address_space(3))) void*)((char*)&As[b][0] + w*2048), 16, 0, 0); \
    __builtin_amdgcn_global_load_lds( \
      (const __attribute__((address_space(1))) void*)&Bg[(size_t)(bn+rowS0)*ldb + (k0) + colS0], \
      (__attribute__((address_space(3))) void*)((char*)&Bs[b][0] + w*2048), 16, 0, 0); \
    __builtin_amdgcn_global_load_lds( \
      (const __attribute__((address_space(1))) void*)&Ag[(size_t)(bm+rowS1)*lda + (k0) + colS1], \
      (__attribute__((address_space(3))) void*)((char*)&As[b][0] + w*2048 + 1024), 16, 0, 0); \
    __builtin_amdgcn_global_load_lds( \
      (const __attribute__((address_space(1))) void*)&Bg[(size_t)(bn+rowS1)*ldb + (k0) + colS1], \
      (__attribute__((address_space(3))) void*)((char*)&Bs[b][0] + w*2048 + 1024), 16, 0, 0); \
  } while(0)

  f32x4 acc[4][4] = {};

  STAGE(0, 0);
  STAGE(32, 1);
  asm volatile("s_waitcnt vmcnt(4)" ::: "memory");
  __builtin_amdgcn_s_barrier();

  int cur = 0, nb = 2;
  for (int k0 = 0; k0 < K; k0 += 32) {
    const bool more = (k0 + 64 < K);
    if (more) STAGE(k0 + 64, nb);

    short8 af[4], bfm[4];
    #pragma unroll
    for (int m=0;m<4;m++) af[m]  = *(const short8*)(&As[cur][(wr*64 + m*16 + lr)*32 + kg*8]);
    #pragma unroll
    for (int n=0;n<4;n++) bfm[n] = *(const short8*)(&Bs[cur][(wc*64 + n*16 + lr)*32 + kg*8]);
    __builtin_amdgcn_s_setprio(1);
    #pragma unroll
    for (int m=0;m<4;m++)
      #pragma unroll
      for (int n=0;n<4;n++)
        acc[m][n] = __builtin_amdgcn_mfma_f32_16x16x32_bf16(af[m], bfm[n], acc[m][n], 0,0,0);
    __builtin_amdgcn_s_setprio(0);

    if (more) { asm volatile("s_waitcnt vmcnt(4)" ::: "memory"); }
    else      { asm volatile("s_waitcnt vmcnt(0)" ::: "memory"); }
    __builtin_amdgcn_s_barrier();
    cur = (cur==2) ? 0 : cur+1;
    nb  = (nb==2)  ? 0 : nb+1;
  }
  #undef STAGE

  // epilogue
  #pragma unroll
  for (int m=0;m<4;m++){
    int row0 = bm + wr*64 + m*16 + kg*4;
    #pragma unroll
    for (int n=0;n<4;n++){
      int col = bn + wc*64 + n*16 + lr;
      float bv = BIAS ? bias[col] : 0.0f;
      #pragma unroll
      for (int r=0;r<4;r++){
        float val = acc[m][n][r] + bv;
        if (RES == 1) val += ((const float*)res)[(size_t)(row0+r)*ldres + col];
        if (RES == 3){
          int grow = row0 + r;
          const float* rs = ((grow % 50) == 0) ? (const float*)res : (const float*)res2;
          val += rs[(size_t)grow*ldres + col];
        }
        if (GELU == 1) val = gelu_fast(val);
        if (OUT_BF16){
          // stage to LDS tile (pitch 132; kg groups 8 banks apart, lr pairs 2-way free)
          int trow = wr*64 + m*16 + kg*4 + r;
          int tcol = wc*64 + n*16 + lr;
          SH[trow*132 + tcol] = bfs(val);
        } else {
          ((float*)Cv)[(size_t)(row0+r)*ldc + col] = val;
        }
      }
    }
  }
  if (OUT_BF16){
    __syncthreads();
    const int r2 = t >> 4, c8 = (t & 15)*8;
    short* Co = (short*)Cv;
    #pragma unroll
    for (int p=0;p<8;p++){
      int row = p*16 + r2;
      short8 v = *(const short8*)&SH[row*132 + c8];
      *(short8*)&Co[(size_t)(bm+row)*ldc + bn + c8] = v;   // 16B/lane, 256B/row-seg
    }
  }
}

#define GEMM_K(NAME, OB, BI, RE, GE) \
__global__ __launch_bounds__(256) void NAME( \
    const bf16* __restrict__ A, const bf16* __restrict__ B, void* Cv, \
    const float* __restrict__ bias, const void* res, const void* res2, \
    int M, int N, int K, int lda, int ldc, int ldres){ \
  gemm_dev<OB,BI,RE,GE>(A,B,Cv,bias,res,res2,M,N,K,lda,K,ldc,ldres); }

GEMM_K(gemm_qkv_k,   true,  false, 0, 0)   // qkv: bf16 out (coalesced epilogue)
GEMM_K(gemm_projc_k, false, true,  1, 0)   // cls proj: +bias, +fp32 res, fp32 out
GEMM_K(gemm_projw_k, false, true,  3, 0)   // window proj: row-conditional residual
GEMM_K(gemm_fc1_k,   true,  true,  0, 1)   // fc1: +bias, fast-gelu, bf16 out
GEMM_K(gemm_wcmb_k,  true,  false, 0, 0)   // weight-combo precompute, bf16 out

// tail keeps explicit ldb=KTAIL plumbing (A lda=KTAIL, B=W_comb ldb=KTAIL)
__global__ __launch_bounds__(256) void gemm_tail_k(
    const bf16* __restrict__ A, const bf16* __restrict__ B, void* Cv,
    const float* __restrict__ bias, const void* res, const void* res2,
    int M, int N, int K, int lda, int ldc, int ldres){
  gemm_dev<false,true,0,0>(A,B,Cv,bias,res,res2,M,N,K,lda,KTAIL,ldc,ldres);
}

// ---------------- cls attention (small; unchanged) ----------------
__global__ __launch_bounds__(256) void attn_cls_kernel(const bf16* __restrict__ qkv,
                                                       bf16* __restrict__ y)
{
  int img = blockIdx.x, h = blockIdx.y;
  __shared__ float q[64][33], k[64][33], v[64][33];
  __shared__ float s[64][65];
  int t = threadIdx.x;
  for (int idx=t; idx<64*32; idx+=256){
    int i = idx>>5, d = idx&31;
    const bf16* base = qkv + ((size_t)(img*64+i))*QKVD + h*32 + d;
    q[i][d] = __bfloat162float(base[0]);
    k[i][d] = __bfloat162float(base[384]);
    v[i][d] = __bfloat162float(base[768]);
  }
  __syncthreads();
  for (int idx=t; idx<64*64; idx+=256){
    int i = idx>>6, j = idx&63;
    float a = 0.f;
    #pragma unroll
    for (int d=0; d<32; d++) a += q[i][d]*k[j][d];
    s[i][j] = a * SCALE_F;
  }
  __syncthreads();
  if (t < 64){
    float m = -1e30f;
    for (int j=0;j<64;j++) m = fmaxf(m, s[t][j]);
    float sum = 0.f;
    for (int j=0;j<64;j++){ float e = __expf(s[t][j]-m); s[t][j]=e; sum+=e; }
    float inv = rcp_fast(sum);
    for (int j=0;j<64;j++) s[t][j] *= inv;
  }
  __syncthreads();
  for (int idx=t; idx<64*32; idx+=256){
    int i = idx>>5, d = idx&31;
    float a = 0.f;
    for (int j=0;j<64;j++) a += s[i][j]*v[j][d];
    y[((size_t)(img*64+i))*CDIM + h*32 + d] = __float2bfloat16(a);
  }
}

// ======== MFMA window attention, head-batched (proven round-17) ========
__global__ __launch_bounds__(128) void attn_win_mfma(const bf16* __restrict__ qkv,
    const float* __restrict__ mask, const float* __restrict__ rel_pos,
    bf16* __restrict__ y)
{
  const int lw = blockIdx.x;
  const int tid = threadIdx.x;
  const int w = tid >> 6;
  const int l = tid & 63;
  const int lr = l & 15, kg = l >> 4;

  __shared__ float msk[2500];
  __shared__ float rp_w[2][169];
  __shared__ short PldsA[2][64*72];
  __shared__ short VTlA[2][32*72];

  const size_t tok0 = (size_t)lw * NTOK;
  const short* qbase = (const short*)qkv;

  for (int i = tid; i < 2500; i += 128) msk[i] = mask[(size_t)lw*2500 + i];
  __syncthreads();

  short* Plds = &PldsA[w][0];
  short* VTl  = &VTlA[w][0];
  float* rp   = &rp_w[w][0];

  for (int hh = 0; hh < 6; hh++){
    const int h = w*6 + hh;

    for (int i = l; i < 169; i += 64) rp[i] = rel_pos[i*NHEADS + h];

    short8 qf[4], kf[4];
    #pragma unroll
    for (int n=0;n<4;n++){
      int qt = 16*n + lr;
      if (qt < 50) qf[n] = *(const short8*)&qbase[(tok0+qt)*QKVD + h*32 + kg*8];
      else         qf[n] = short8(0);
    }
    #pragma unroll
    for (int m=0;m<4;m++){
      int kt = 16*m + lr;
      if (kt < 50) kf[m] = *(const short8*)&qbase[(tok0+kt)*QKVD + 384 + h*32 + kg*8];
      else         kf[m] = short8(0);
    }

    {
      short vv[32];
      if (l < 50){
        const short8* vp = (const short8*)&qbase[(tok0+l)*QKVD + 768 + h*32];
        #pragma unroll
        for (int jj=0;jj<4;jj++){ short8 xv = vp[jj];
          #pragma unroll
          for (int e=0;e<8;e++) vv[jj*8+e] = xv[e]; }
      } else {
        #pragma unroll
        for (int d=0; d<32; d++) vv[d]=0;
      }
      #pragma unroll
      for (int d=0; d<32; d++) VTl[d*72 + l] = vv[d];
    }

    f32x4 sacc[4][4] = {};
    #pragma unroll
    for (int m=0;m<4;m++)
      #pragma unroll
      for (int n=0;n<4;n++)
        sacc[m][n] = __builtin_amdgcn_mfma_f32_16x16x32_bf16(kf[m], qf[n], sacc[m][n], 0,0,0);

    float sv[4][4][4];
    #pragma unroll
    for (int m=0;m<4;m++){
      #pragma unroll
      for (int r=0;r<4;r++){
        int kt = 16*m + 4*kg + r;
        #pragma unroll
        for (int n=0;n<4;n++){
          int qt = 16*n + lr;
          float a;
          if (kt < 50 && qt < 50){
            a = sacc[m][n][r] * SCALE_F;
            if (kt>=1 && qt>=1){
              int qi=qt-1, kj=kt-1;
              int ridx = ((qi/7)-(kj/7)+6)*13 + (qi%7)-(kj%7)+6;
              a += rp[ridx];
            }
            a += msk[qt*50+kt];
          } else a = -1e30f;
          sv[m][r][n] = a;
        }
      }
    }

    #pragma unroll
    for (int n=0;n<4;n++){
      float mx = -1e30f;
      #pragma unroll
      for (int m=0;m<4;m++)
        #pragma unroll
        for (int r=0;r<4;r++) mx = fmaxf(mx, sv[m][r][n]);
      mx = fmaxf(mx, __shfl_xor(mx, 16));
      mx = fmaxf(mx, __shfl_xor(mx, 32));
      float sum = 0.f;
      float pv[4][4];
      #pragma unroll
      for (int m=0;m<4;m++)
        #pragma unroll
        for (int r=0;r<4;r++){ float p = __expf(sv[m][r][n]-mx); pv[m][r]=p; sum+=p; }
      sum += __shfl_xor(sum, 16);
      sum += __shfl_xor(sum, 32);
      float inv = rcp_fast(sum);
      int qrow = (16*n + lr)*72;
      #pragma unroll
      for (int m=0;m<4;m++){
        short4v pk;
        #pragma unroll
        for (int r=0;r<4;r++) pk[r] = bfs(pv[m][r]*inv);
        *(short4v*)&Plds[qrow + 16*m + 4*kg] = pk;
      }
    }

    f32x4 oacc[2][4] = {};
    #pragma unroll
    for (int ks=0; ks<2; ks++){
      short8 pf[4];
      #pragma unroll
      for (int n=0;n<4;n++)
        pf[n] = *(const short8*)&Plds[(16*n+lr)*72 + 32*ks + kg*8];
      #pragma unroll
      for (int md=0; md<2; md++){
        short8 vf = *(const short8*)&VTl[(16*md+lr)*72 + 32*ks + kg*8];
        #pragma unroll
        for (int n=0;n<4;n++)
          oacc[md][n] = __builtin_amdgcn_mfma_f32_16x16x32_bf16(vf, pf[n], oacc[md][n], 0,0,0);
      }
    }

    short* yb = (short*)y;
    #pragma unroll
    for (int n=0;n<4;n++){
      int qt = 16*n + lr;
      if (qt >= 50) continue;
      #pragma unroll
      for (int md=0; md<2; md++){
        short4v pk;
        #pragma unroll
        for (int r=0;r<4;r++) pk[r] = bfs(oacc[md][n][r]);
        *(short4v*)&yb[(tok0+qt)*CDIM + h*32 + 16*md + 4*kg] = pk;
      }
    }
  }
}

// ---------------------------------------------------------------------------
extern "C" void kernel_launch(void* const* d_in, const int* in_sizes, int n_in,
                              void* d_out, int out_size, void* d_ws, size_t ws_size,
                              hipStream_t stream)
{
  const float* x_in   = (const float*)d_in[0];
  const float* maskp  = (const float*)d_in[1];
  const float* g0 = (const float*)d_in[2];  const float* b0 = (const float*)d_in[3];
  const float* g1 = (const float*)d_in[4];  const float* b1 = (const float*)d_in[5];
  const float* g2 = (const float*)d_in[6];  const float* b2 = (const float*)d_in[7];
  const float* ge = (const float*)d_in[8];  const float* be = (const float*)d_in[9];
  const float* w_qkv = (const float*)d_in[10];
  const float* w_proj= (const float*)d_in[11];
  const float* b_proj= (const float*)d_in[12];
  const float* rel_pos=(const float*)d_in[13];
  const float* w_fc1 = (const float*)d_in[14];
  const float* b_fc1 = (const float*)d_in[15];
  const float* w_fc2 = (const float*)d_in[16];
  const float* b_fc2 = (const float*)d_in[17];
  const float* w_exp = (const float*)d_in[18];
  const float* b_exp = (const float*)d_in[19];
  const float* w_lin = (const float*)d_in[20];
  const float* b_lin = (const float*)d_in[21];
  float* dout = (float*)d_out;

  const size_t NT = (size_t)NWIN * NTOK;

  size_t off = 0;
  auto alloc = [&](size_t bytes)->void* {
    void* p = (char*)d_ws + off;
    off += (bytes + 255) & ~(size_t)255;
    return p;
  };

  bf16* wqkv_b = (bf16*)alloc((size_t)QKVD*CDIM*2);
  bf16* wproj_b= (bf16*)alloc((size_t)CDIM*CDIM*2);
  bf16* wfc1_b = (bf16*)alloc((size_t)MLPH*CDIM*2);
  bf16* wlin_b = (bf16*)alloc((size_t)CDIM*DHID*2);
  bf16* wexpT_b= (bf16*)alloc((size_t)CDIM*DHID*2);
  bf16* wfc2T_b= (bf16*)alloc((size_t)MLPH*DHID*2);
  bf16* W_comb = (bf16*)alloc((size_t)CDIM*KTAIL*2);
  float* biasc = (float*)alloc((size_t)CDIM*4);
  float* xb    = (float*)alloc(NT*CDIM*4);
  bf16* clsln  = (bf16*)alloc((size_t)NWIN*CDIM*2);
  bf16* qkvcls = (bf16*)alloc((size_t)NWIN*QKVD*2);
  bf16* ycls   = (bf16*)alloc((size_t)NWIN*CDIM*2);

  // per-window: xln 38400 + ybfc 38400 + h1ext 345600 = 422400 (qkvc aliases h1ext)
  int CH_W = 2048;
  const size_t per_window = 422400ull;
  while (CH_W > 128 && off + (size_t)CH_W*per_window + 16384 > ws_size) CH_W >>= 1;
  const int CH_T = CH_W * NTOK;

  bf16*  xln   = (bf16*) alloc((size_t)CH_T*CDIM*2);
  bf16*  ybfc  = (bf16*) alloc((size_t)CH_T*CDIM*2);
  bf16*  h1ext = (bf16*) alloc((size_t)CH_T*KTAIL*2);
  bf16*  qkvc  = h1ext;   // alias: qkvc dead before h1ext is written

  // ---- precompute ----
  cvt4_kernel<<<512, 256, 0, stream>>>(
      w_qkv, wqkv_b, QKVD*CDIM,  w_proj, wproj_b, CDIM*CDIM,
      w_fc1, wfc1_b, MLPH*CDIM,  w_lin,  wlin_b,  CDIM*DHID);
  transpose_cvt_kernel<<<dim3(CDIM/32, DHID/32), 256, 0, stream>>>(w_exp, wexpT_b, DHID, CDIM);
  transpose_cvt_kernel<<<dim3(MLPH/32, DHID/32), 256, 0, stream>>>(w_fc2, wfc2T_b, DHID, MLPH);
  bias_combine_kernel<<<6, 64, 0, stream>>>(w_lin, b_lin, b_exp, b_fc2, biasc);
  gemm_wcmb_k<<<dim3(CDIM/128, CDIM/128), 256, 0, stream>>>(
      wlin_b, wexpT_b, W_comb, nullptr, nullptr, nullptr, CDIM, CDIM, DHID, DHID, KTAIL, 0);
  gemm_wcmb_k<<<dim3(MLPH/128, CDIM/128), 256, 0, stream>>>(
      wlin_b, wfc2T_b, W_comb + 384, nullptr, nullptr, nullptr, CDIM, MLPH, DHID, DHID, KTAIL, 0);

  // ---- cls path (writes only cls rows of xb) ----
  ln_kernel<false><<<NWIN/4, 256, 0, stream>>>(x_in, (long)NTOK*CDIM, g0, b0, clsln, NWIN);
  gemm_qkv_k<<<dim3(QKVD/128, NWIN/128), 256, 0, stream>>>(
      clsln, wqkv_b, qkvcls, nullptr, nullptr, nullptr, NWIN, QKVD, CDIM, CDIM, QKVD, 0);
  attn_cls_kernel<<<dim3(IMGS, NHEADS), 256, 0, stream>>>(qkvcls, ycls);
  gemm_projc_k<<<dim3(CDIM/128, NWIN/128), 256, 0, stream>>>(
      ycls, wproj_b, xb, b_proj, x_in, nullptr, NWIN, CDIM, CDIM, CDIM, NTOK*CDIM, NTOK*CDIM);

  // ---- main chunk loop ----
  const int nch = NWIN / CH_W;
  for (int c = 0; c < nch; c++){
    int w0 = c * CH_W;
    size_t t0 = (size_t)w0 * NTOK;
    float* xbc = xb + t0*CDIM;
    const float* xinc = x_in + t0*CDIM;
    float* doutc = dout + t0*CDIM;
    int MT = CH_T, MB = CH_T/128;

    ln_sel_kernel<<<MT/4, 256, 0, stream>>>(xbc, xinc, g1, b1, xln, MT);
    gemm_qkv_k<<<dim3(QKVD/128, MB), 256, 0, stream>>>(
        xln, wqkv_b, qkvc, nullptr, nullptr, nullptr, MT, QKVD, CDIM, CDIM, QKVD, 0);
    attn_win_mfma<<<dim3(CH_W), 128, 0, stream>>>(
        qkvc, maskp + (size_t)w0*2500, rel_pos, ybfc);
    gemm_projw_k<<<dim3(CDIM/128, MB), 256, 0, stream>>>(
        ybfc, wproj_b, xbc, b_proj, xbc, xinc, MT, CDIM, CDIM, CDIM, CDIM, CDIM);

    // ---- MLP pipeline sub-chunked so each h1ext slice stays L3-resident ----
    const int NSUB = (CH_W >= 1024) ? 2 : 1;
    const int MS = MT / NSUB, MSB = MS / 128;
    for (int s = 0; s < NSUB; s++){
      size_t r0 = (size_t)s * MS;
      float* xbs = xbc + r0*CDIM;
      bf16*  h1s = h1ext + r0*KTAIL;
      bf16*  ybs = ybfc + r0*CDIM;
      float* dos = doutc + r0*CDIM;

      ln_dual_kernel<<<MS/4, 256, 0, stream>>>(xbs, ge, be, g2, b2, h1s, KTAIL, ybs, MS);

      gemm_fc1_k<<<dim3(MLPH/128, MSB), 256, 0, stream>>>(
          ybs, wfc1_b, h1s + 384, b_fc1, nullptr, nullptr, MS, MLPH, CDIM, CDIM, KTAIL, 0);

      gemm_tail_k<<<dim3(CDIM/128, MSB), 256, 0, stream>>>(
          h1s, W_comb, dos, biasc, nullptr, nullptr, MS, CDIM, KTAIL, KTAIL, CDIM, 0);
    }
  }
}